// Round 13
// baseline (557.787 us; speedup 1.0000x reference)
//
#include <hip/hip_runtime.h>

typedef unsigned short u16;
typedef unsigned int   u32;
using bf16x8 = __attribute__((ext_vector_type(8))) __bf16;
using f32x4  = __attribute__((ext_vector_type(4))) float;
using f32x16 = __attribute__((ext_vector_type(16))) float;
using u32x4  = __attribute__((ext_vector_type(4))) unsigned int;
using ushort8 = __attribute__((ext_vector_type(8))) unsigned short;

// B=2, S=2048, D=4096, H=32, KV=8, HD=128 hardcoded throughout.

__device__ __forceinline__ u16 f2bf(float f) {
  u32 u = __builtin_bit_cast(u32, f);
  return (u16)((u + 0x7fffu + ((u >> 16) & 1u)) >> 16);
}
__device__ __forceinline__ float bf2f(u16 h) {
  return __builtin_bit_cast(float, (u32)h << 16);
}
__device__ __forceinline__ f32x4 mfma16(bf16x8 a, bf16x8 b, f32x4 c) {
  return __builtin_amdgcn_mfma_f32_16x16x32_bf16(a, b, c, 0, 0, 0);
}
__device__ __forceinline__ f32x16 mfma32(bf16x8 a, bf16x8 b, f32x16 c) {
  return __builtin_amdgcn_mfma_f32_32x32x16_bf16(a, b, c, 0, 0, 0);
}
__device__ __forceinline__ f32x16 zero16() {
  f32x16 z;
#pragma unroll
  for (int i = 0; i < 16; ++i) z[i] = 0.f;
  return z;
}
__device__ __forceinline__ void g2l16(const void* gp, void* lp) {
  __builtin_amdgcn_global_load_lds(
      (__attribute__((address_space(1))) void*)(void*)gp,
      (__attribute__((address_space(3))) void*)lp, 16, 0, 0);
}

// ---------------- fp32 -> bf16 elementwise ----------------
__global__ void k_cvt(const float* __restrict__ in, u16* __restrict__ out, int n4) {
  int i = blockIdx.x * 256 + threadIdx.x;
  if (i >= n4) return;
  float4 v = ((const float4*)in)[i];
  ushort4 o;
  o.x = f2bf(v.x); o.y = f2bf(v.y); o.z = f2bf(v.z); o.w = f2bf(v.w);
  ((ushort4*)out)[i] = o;
}

// ---------------- fp32 (K,N)->(N,K) transpose-convert, 64x64 tile core ----------------
__device__ __forceinline__ void tcvt_tile(const float* __restrict__ in, u16* __restrict__ out,
                                          int K, int N, int nt, int kt, u16 (*t)[72]) {
  const int n0 = nt * 64, k0 = kt * 64;
  const int tid = threadIdx.x;
  const int r = tid >> 2, c4 = (tid & 3) * 16;
  const float* src = in + (size_t)(k0 + r) * N + n0 + c4;
#pragma unroll
  for (int q = 0; q < 4; ++q) {
    float4 v = *(const float4*)(src + 4 * q);
    t[c4 + 4 * q + 0][r] = f2bf(v.x);
    t[c4 + 4 * q + 1][r] = f2bf(v.y);
    t[c4 + 4 * q + 2][r] = f2bf(v.z);
    t[c4 + 4 * q + 3][r] = f2bf(v.w);
  }
  __syncthreads();
  u16* dst = out + (size_t)(n0 + r) * K + k0 + c4;
#pragma unroll
  for (int hh = 0; hh < 2; ++hh)
    *(ushort8*)(dst + 8 * hh) = *(const ushort8*)(&t[r][c4 + 8 * hh]);
}

__global__ __launch_bounds__(256) void k_tcvt(const float* __restrict__ in, u16* __restrict__ out,
                                              int K, int N) {
  __shared__ u16 t[64][72];
  tcvt_tile(in, out, K, N, blockIdx.x, blockIdx.y, t);
}

__global__ __launch_bounds__(256) void k_tcvt5(const float* __restrict__ Wq, const float* __restrict__ Wk0,
                                               const float* __restrict__ Wv0, const float* __restrict__ Wk1,
                                               const float* __restrict__ Wv1, u16* __restrict__ WqT,
                                               u16* __restrict__ Wkv0T, u16* __restrict__ Wkv1T) {
  __shared__ u16 t[64][72];
  int bid = blockIdx.x;
  if (bid < 4096) {
    tcvt_tile(Wq, WqT, 4096, 4096, bid & 63, bid >> 6, t);
  } else {
    int r = bid - 4096;
    int mat = r >> 10, rr = r & 1023;
    const float* src = (mat == 0) ? Wk0 : (mat == 1) ? Wv0 : (mat == 2) ? Wk1 : Wv1;
    u16* dst = (mat == 0) ? Wkv0T : (mat == 1) ? (Wkv0T + (size_t)1024 * 4096)
                                  : (mat == 2) ? Wkv1T : (Wkv1T + (size_t)1024 * 4096);
    tcvt_tile(src, dst, 4096, 1024, rr & 15, rr >> 4, t);
  }
}

// ---------------- modality scan ----------------
__global__ void k_scan(const int* __restrict__ mod, int* __restrict__ perm, int* __restrict__ meta) {
  __shared__ int ps[1024];
  const int b = blockIdx.x, t = threadIdx.x;
  perm[b * 2304 + t] = -1;
  perm[b * 2304 + 1024 + t] = -1;
  if (t < 256) perm[b * 2304 + 2048 + t] = -1;
  const int i0 = 2 * t, i1 = 2 * t + 1;
  const int f0 = (mod[b * 2048 + i0] != 1) ? 1 : 0;
  const int f1 = (mod[b * 2048 + i1] != 1) ? 1 : 0;
  const int sum = f0 + f1;
  ps[t] = sum;
  __syncthreads();
  for (int off = 1; off < 1024; off <<= 1) {
    int v = (t >= off) ? ps[t - off] : 0;
    __syncthreads();
    ps[t] += v;
    __syncthreads();
  }
  const int total0 = ps[1023];
  const int excl = ps[t] - sum;
  const int nt0 = (total0 + 255) >> 8;
  const int off1 = nt0 * 256;
  const int s0 = f0 ? excl : off1 + (i0 - excl);
  const int s1 = f1 ? (excl + f0) : off1 + (i1 - (excl + f0));
  perm[b * 2304 + s0] = i0;
  perm[b * 2304 + s1] = i1;
  if (t == 0) { meta[b * 2] = total0; meta[b * 2 + 1] = nt0; }
}

// ================= 8-phase 256x256 bf16 GEMM core (K=4096), 512 thr (r12, for k_gemm8) ==========
#define BARSB() { __builtin_amdgcn_s_barrier(); __builtin_amdgcn_sched_barrier(0); }
#define VMC(N)  asm volatile("s_waitcnt vmcnt(" #N ")" ::: "memory")

#define READ_A(MH, SL) { _Pragma("unroll") for (int mf_ = 0; mf_ < 4; ++mf_) {       \
    const char* a_ = (const char*)lds8 + (SL)*65536 + (MH)*16384 + (arow + mf_*16)*128; \
    afr[mf_][0] = *(const bf16x8*)(a_ + swc0);                                        \
    afr[mf_][1] = *(const bf16x8*)(a_ + swc1); } }

#define READ_B(NH, SL) { _Pragma("unroll") for (int nf_ = 0; nf_ < 2; ++nf_) {       \
    const char* b_ = (const char*)lds8 + (SL)*65536 + 32768 + (NH)*16384 + (brow + nf_*16)*128; \
    bfr[nf_][0] = *(const bf16x8*)(b_ + swc0);                                        \
    bfr[nf_][1] = *(const bf16x8*)(b_ + swc1); } }

#define MM16(MH, NH) { __builtin_amdgcn_s_setprio(1);                                 \
  _Pragma("unroll") for (int mf_ = 0; mf_ < 4; ++mf_)                                 \
    _Pragma("unroll") for (int nf_ = 0; nf_ < 2; ++nf_) {                             \
      acc[MH][mf_][NH][nf_] = mfma16(afr[mf_][0], bfr[nf_][0], acc[MH][mf_][NH][nf_]); \
      acc[MH][mf_][NH][nf_] = mfma16(afr[mf_][1], bfr[nf_][1], acc[MH][mf_][NH][nf_]); } \
  __builtin_amdgcn_s_setprio(0); }

#define STAGE_A(T, MH) { int ts_ = (T) < 64 ? (T) : 63;                               \
    char* d_ = (char*)lds8 + ((T)&1)*65536 + (MH)*16384 + wid*1024;                   \
    g2l16(pA0[MH] + ts_*64, d_); g2l16(pA1[MH] + ts_*64, d_ + 8192); }

#define STAGE_B(T, NH) { int ts_ = (T) < 64 ? (T) : 63;                               \
    char* d_ = (char*)lds8 + ((T)&1)*65536 + 32768 + (NH)*16384 + wid*1024;           \
    g2l16(pB0[NH] + ts_*64, d_); g2l16(pB1[NH] + ts_*64, d_ + 8192); }

#define G8_MAINLOOP()                                                                 \
  STAGE_A(0,0); STAGE_B(0,1); STAGE_A(0,1); STAGE_B(0,0);                             \
  STAGE_A(1,0); STAGE_B(1,1); STAGE_A(1,1);                                           \
  VMC(6); BARSB();                                                                    \
  for (int i_ = 0; i_ < 32; ++i_) {                                                   \
    const int ta_ = 2 * i_;                                                           \
    READ_A(0,0); READ_B(0,0); STAGE_B(ta_+1, 0); BARSB(); MM16(0,0); BARSB();         \
    READ_B(1,0);              STAGE_A(ta_+2, 0); BARSB(); MM16(0,1); BARSB();         \
    READ_A(1,0);              STAGE_B(ta_+2, 1); BARSB(); MM16(1,1); BARSB();         \
    READ_B(0,0);              STAGE_A(ta_+2, 1); BARSB(); MM16(1,0); VMC(4); BARSB(); \
    READ_A(0,1); READ_B(0,1); STAGE_B(ta_+2, 0); BARSB(); MM16(0,0); BARSB();         \
    READ_B(1,1);              STAGE_A(ta_+3, 0); BARSB(); MM16(0,1); BARSB();         \
    READ_A(1,1);              STAGE_B(ta_+3, 1); BARSB(); MM16(1,1); BARSB();         \
    READ_B(0,1);              STAGE_A(ta_+3, 1); BARSB(); MM16(1,0); VMC(4); BARSB(); \
  }

// ---- O-projection GEMM: fp32 row-major out (8-phase core) ----
__global__ __launch_bounds__(512, 2) void k_gemm8(const u16* __restrict__ A, const u16* __restrict__ Bt,
                                                  float* __restrict__ Cp) {
  __shared__ u16 lds8[65536];  // 128 KB
  const int tid = threadIdx.x, wid = tid >> 6, l = tid & 63, g = l >> 4, li = l & 15;
  const int wr = wid >> 2, wc = wid & 3;
  const int bid = blockIdx.x;
  const int swz = (bid & 7) * 32 + (bid >> 3);
  const int m0 = (swz >> 4) * 256, n0 = (swz & 15) * 256;

  const int swc0 = (g * 16) ^ ((li & 7) << 4);
  const int swc1 = (64 + g * 16) ^ ((li & 7) << 4);
  const int arow = wr * 64 + li;
  const int brow = wc * 32 + li;

  const int l8a = tid * 16, l8b = 8192 + tid * 16;
  const int oa = l8a ^ (((l8a >> 7) & 7) << 4), ob = l8b ^ (((l8b >> 7) & 7) << 4);
  const int rl0 = oa >> 7, cb0 = oa & 127, rl1 = ob >> 7, cb1 = ob & 127;
  const int RA0 = (rl0 >> 6) * 128 + (rl0 & 63), RA1 = (rl1 >> 6) * 128 + (rl1 & 63);
  const int CB0 = (rl0 >> 5) * 64 + (rl0 & 31), CB1 = (rl1 >> 5) * 64 + (rl1 & 31);
  const u16 *pA0[2], *pA1[2], *pB0[2], *pB1[2];
#pragma unroll
  for (int mh = 0; mh < 2; ++mh) {
    pA0[mh] = A + (size_t)(m0 + RA0 + mh * 64) * 4096 + cb0 / 2;
    pA1[mh] = A + (size_t)(m0 + RA1 + mh * 64) * 4096 + cb1 / 2;
    pB0[mh] = Bt + (size_t)(n0 + CB0 + mh * 32) * 4096 + cb0 / 2;
    pB1[mh] = Bt + (size_t)(n0 + CB1 + mh * 32) * 4096 + cb1 / 2;
  }

  bf16x8 afr[4][2], bfr[2][2];
  const f32x4 vzero = {0.f, 0.f, 0.f, 0.f};
  f32x4 acc[2][4][2][2];
#pragma unroll
  for (int a = 0; a < 2; ++a)
#pragma unroll
    for (int b = 0; b < 4; ++b)
#pragma unroll
      for (int c = 0; c < 2; ++c)
#pragma unroll
        for (int d = 0; d < 2; ++d) acc[a][b][c][d] = vzero;

  G8_MAINLOOP();

#pragma unroll
  for (int mh = 0; mh < 2; ++mh)
#pragma unroll
    for (int mf = 0; mf < 4; ++mf)
#pragma unroll
      for (int nh = 0; nh < 2; ++nh)
#pragma unroll
        for (int nf = 0; nf < 2; ++nf)
#pragma unroll
          for (int j = 0; j < 4; ++j) {
            int row = m0 + wr * 128 + mh * 64 + mf * 16 + g * 4 + j;
            int col = n0 + wc * 64 + nh * 32 + nf * 16 + li;
            Cp[(size_t)row * 4096 + col] = acc[mh][mf][nh][nf][j];
          }
}

// ================= r9 16-wave GEMM core (1024 thr, 4-slot, vmcnt4) for QKV ==================
#define TB16(T, VMLIT, DOSTAGE)                                              \
  {                                                                          \
    asm volatile("s_waitcnt vmcnt(" VMLIT ")" ::: "memory");                 \
    __builtin_amdgcn_s_barrier();                                            \
    __builtin_amdgcn_sched_barrier(0);                                       \
    const u16* base_ = lds + ((T) & 3) * 16384;                              \
    bf16x8 bfr[4], afr[4];                                                   \
    _Pragma("unroll")                                                        \
    for (int nf = 0; nf < 4; ++nf)                                           \
      bfr[nf] = *(const bf16x8*)(base_ + boff + nf * 512);                   \
    _Pragma("unroll")                                                        \
    for (int mf = 0; mf < 4; ++mf)                                           \
      afr[mf] = *(const bf16x8*)(base_ + aoff + mf * 512);                   \
    if (DOSTAGE) stage((T) + 3);                                             \
    __builtin_amdgcn_s_setprio(1);                                           \
    _Pragma("unroll")                                                        \
    for (int mf = 0; mf < 4; ++mf)                                           \
      _Pragma("unroll")                                                      \
      for (int nf = 0; nf < 4; ++nf)                                         \
        acc[mf][nf] = mfma16(afr[mf], bfr[nf], acc[mf][nf]);                 \
    __builtin_amdgcn_s_setprio(0);                                           \
  }

#define LOOP16()                                                             \
  stage(0); stage(1); stage(2);                                              \
  for (int t = 0; t < 125; ++t) TB16(t, "4", true);                          \
  TB16(125, "4", false);                                                     \
  TB16(126, "2", false);                                                     \
  TB16(127, "0", false);

// ---- merged Q + segmented-KV GEMM, 400 blocks, 1024 thr (r9 core) ----
__global__ __launch_bounds__(1024, 4) void k_gemmQKV(const u16* __restrict__ Xb, const u16* __restrict__ WqT,
                                                     const u16* __restrict__ B0, const u16* __restrict__ B1,
                                                     const int* __restrict__ perm, const int* __restrict__ meta,
                                                     u16* __restrict__ Qr, u16* __restrict__ Ksel,
                                                     u16* __restrict__ Vsel) {
  __shared__ u16 lds[4 * 16384];
  const int tid = threadIdx.x, wid = tid >> 6, l = tid & 63, g = l >> 4, li = l & 15;
  const int wr = wid >> 2, wc = wid & 3;
  const int bid = blockIdx.x;
  const bool isQ = bid < 256;

  const int srow = wid * 16 + (l >> 2);
  const int sgg = (l & 3) ^ ((l >> 3) & 3);

  int m0 = 0, n0 = 0, bb = 0, tm = 0;
  const u16 *pA, *pB;
  if (isQ) {
    const int swz = (bid & 7) * 32 + (bid >> 3);
    m0 = (swz >> 4) * 256; n0 = (swz & 15) * 256;
    pA = Xb + (size_t)(m0 + srow) * 4096 + sgg * 8;
    pB = WqT + (size_t)(n0 + srow) * 4096 + sgg * 8;
  } else {
    const int kb = bid - 256;
    const int seg = kb >> 3;
    n0 = (kb & 7) * 256;
    bb = seg / 9; tm = seg % 9;
    const int nt0 = meta[bb * 2 + 1];
    const u16* Bt = (tm >= nt0) ? B1 : B0;
    int t0 = perm[bb * 2304 + tm * 256 + srow];
    if (t0 < 0) t0 = 0;
    pA = Xb + ((size_t)bb * 2048 + t0) * 4096 + sgg * 8;
    pB = Bt + (size_t)(n0 + srow) * 4096 + sgg * 8;
  }

  auto stage = [&](int t) {
    u16* da = (u16*)lds + (t & 3) * 16384 + wid * 512;
    g2l16(pA + t * 32, da);
    g2l16(pB + t * 32, da + 8192);
  };

  const int lsl8 = (g ^ ((li >> 1) & 3)) * 8;
  const int aoff = (wr * 64 + li) * 32 + lsl8;
  const int boff = 8192 + (wc * 64 + li) * 32 + lsl8;

  const f32x4 vzero = {0.f, 0.f, 0.f, 0.f};
  f32x4 acc[4][4];
#pragma unroll
  for (int m = 0; m < 4; ++m)
#pragma unroll
    for (int n = 0; n < 4; ++n) acc[m][n] = vzero;

  LOOP16();

  if (isQ) {
#pragma unroll
    for (int mf = 0; mf < 4; ++mf)
#pragma unroll
      for (int nf = 0; nf < 4; ++nf)
#pragma unroll
        for (int j = 0; j < 4; ++j) {
          int row = m0 + wr * 64 + mf * 16 + g * 4 + j;
          int col = n0 + wc * 64 + nf * 16 + li;
          int b = row >> 11, s = row & 2047, h = col >> 7, d = col & 127;
          Qr[(((size_t)(b * 32 + h)) * 2048 + s) * 128 + d] = f2bf(acc[mf][nf][j]);
        }
  } else {
#pragma unroll
    for (int mf = 0; mf < 4; ++mf)
#pragma unroll
      for (int nf = 0; nf < 4; ++nf)
#pragma unroll
        for (int j = 0; j < 4; ++j) {
          int slot = tm * 256 + wr * 64 + mf * 16 + g * 4 + j;
          int tok = perm[bb * 2304 + slot];
          if (tok >= 0) {
            int col = n0 + wc * 64 + nf * 16 + li;   // 0..2047
            int kv = col >> 10, hh = (col >> 7) & 7, d = col & 127;
            u16* dst = (kv ? Vsel : Ksel) + (((size_t)(bb * 8 + hh)) * 2048 + tok) * 128 + d;
            *dst = f2bf(acc[mf][nf][j]);
          }
        }
  }
}

// ---------------- merged: RoPE(Q) + [RoPE(K) + V transpose] ----------------
__global__ __launch_bounds__(256) void k_ropekv(u16* __restrict__ Q, const u16* __restrict__ Ks,
                                                const u16* __restrict__ Vs, const int* __restrict__ pos,
                                                u16* __restrict__ Kr, u16* __restrict__ Vt) {
  __shared__ u16 Vl[64][136];
  const int bid = blockIdx.x;
  const int tid = threadIdx.x, l = tid & 63;
  const float invf = expf((float)l * -0.14391156831212787f);
  if (bid < 32768) {
    int row = bid * 4 + (tid >> 6);
    int s = row & 2047;
    u16* p = Q + (size_t)row * 128;
    float x1 = bf2f(p[l]), x2 = bf2f(p[l + 64]);
    float ang = (float)pos[s] * invf;
    float cs = cosf(ang), sn = sinf(ang);
    const float sc = 0.08838834764831845f;
    p[l] = f2bf((x1 * cs - x2 * sn) * sc);
    p[l + 64] = f2bf((x2 * cs + x1 * sn) * sc);
  } else {
    int blk = bid - 32768;
    int st = blk & 31, kvh = (blk >> 5) & 7, b = blk >> 8;
    int s0 = st * 64;
    int wid = tid >> 6;
    size_t slab = (size_t)(b * 8 + kvh) * 2048;
    for (int rr = 0; rr < 16; ++rr) {
      int r = wid * 16 + rr;
      int s = s0 + r;
      const u16* ks = Ks + (slab + s) * 128;
      const u16* vs = Vs + (slab + s) * 128;
      float ang = (float)pos[s] * invf;
      float cs = cosf(ang), sn = sinf(ang);
      float x1 = bf2f(ks[l]), x2 = bf2f(ks[l + 64]);
      u16* kd = Kr + (slab + s) * 128;
      kd[l] = f2bf(x1 * cs - x2 * sn);
      kd[l + 64] = f2bf(x2 * cs + x1 * sn);
      Vl[r][l] = vs[l];
      Vl[r][l + 64] = vs[l + 64];
    }
    __syncthreads();
    int d = tid >> 1, si0 = (tid & 1) * 32;
    u16* vd = Vt + ((size_t)(b * 8 + kvh) * 128 + d) * 2048 + s0 + si0;
#pragma unroll
    for (int k4 = 0; k4 < 8; ++k4) {
      ushort4 o;
      o.x = Vl[si0 + k4 * 4 + 0][d];
      o.y = Vl[si0 + k4 * 4 + 1][d];
      o.z = Vl[si0 + k4 * 4 + 2][d];
      o.w = Vl[si0 + k4 * 4 + 3][d];
      *(ushort4*)(vd + k4 * 4) = o;
    }
  }
}

// ---------------- attention: T15 QK-prefetch pipeline, K 3-ring / V 2-ring, XCD-affinity ----------------
// Per iteration kt: QK(kt+1) MFMAs issue BEFORE softmax(kt)'s VALU chain (overlap on
// separate pipes), then PV(kt). K staged 3 ahead (slots kt%3), V 2 ahead (kt%2); LDS
// 48+32=80KB -> 2 blocks/CU. vmcnt(8) at tile top drains exactly {K(kt+1), V(kt)}.
#define QKT(ST, KT)                                                            \
  if ((KT) < nkt && (KT) * 64 <= q0 + w * 32 + 31) {                           \
    ST[0] = zero16(); ST[1] = zero16();                                        \
    const char* kb_ = (const char*)Kl + ((KT) % 3) * 16384;                    \
    _Pragma("unroll")                                                          \
    for (int kk = 0; kk < 8; ++kk) {                                           \
      bf16x8 k0_, k1_;                                                         \
      { int r_ = lo5;                                                          \
        k0_ = *(const bf16x8*)(kb_ + r_ * 256 + ((kk * 32 + hi * 16) ^ ((r_ & 15) << 4))); } \
      { int r_ = 32 + lo5;                                                     \
        k1_ = *(const bf16x8*)(kb_ + r_ * 256 + ((kk * 32 + hi * 16) ^ ((r_ & 15) << 4))); } \
      __builtin_amdgcn_s_setprio(1);                                           \
      ST[0] = mfma32(k0_, qf[kk], ST[0]);                                      \
      ST[1] = mfma32(k1_, qf[kk], ST[1]);                                      \
      __builtin_amdgcn_s_setprio(0);                                           \
    }                                                                          \
  }

#define SOFTPV(ST, KT)                                                         \
  if ((KT) * 64 <= q0 + w * 32 + 31) {                                         \
    const int ktb_ = (KT) * 64;                                                \
    if (ktb_ + 63 > q0 + w * 32) {                                             \
      _Pragma("unroll")                                                        \
      for (int mf = 0; mf < 2; ++mf)                                           \
        _Pragma("unroll")                                                      \
        for (int r = 0; r < 16; ++r) {                                         \
          int kg = ktb_ + mf * 32 + (r & 3) + 8 * (r >> 2) + 4 * hi;           \
          if (kg > qlane) ST[mf][r] = -3.0e38f;                                \
        }                                                                      \
    }                                                                          \
    float t_[16];                                                              \
    _Pragma("unroll")                                                          \
    for (int r = 0; r < 16; ++r) t_[r] = fmaxf(ST[0][r], ST[1][r]);            \
    _Pragma("unroll")                                                          \
    for (int s = 8; s >= 1; s >>= 1)                                           \
      _Pragma("unroll")                                                        \
      for (int r = 0; r < s; ++r) t_[r] = fmaxf(t_[r], t_[r + s]);             \
    float pmax = fmaxf(t_[0], __shfl_xor(t_[0], 32));                          \
    if (!__all(pmax <= m + 8.f)) {                                             \
      float nm = fmaxf(m, pmax);                                               \
      float resc = exp2f((m - nm) * L2E);                                      \
      m = nm;                                                                  \
      ls *= resc;                                                              \
      _Pragma("unroll")                                                        \
      for (int i = 0; i < 4; ++i)                                              \
        _Pragma("unroll")                                                      \
        for (int r = 0; r < 16; ++r) ot[i][r] *= resc;                         \
    }                                                                          \
    _Pragma("unroll")                                                          \
    for (int mf = 0; mf < 2; ++mf)                                             \
      _Pragma("unroll")                                                        \
      for (int r = 0; r < 16; ++r) ST[mf][r] = exp2f((ST[mf][r] - m) * L2E);   \
    float u_[16];                                                              \
    _Pragma("unroll")                                                          \
    for (int r = 0; r < 16; ++r) u_[r] = ST[0][r] + ST[1][r];                  \
    _Pragma("unroll")                                                          \
    for (int s = 8; s >= 1; s >>= 1)                                           \
      _Pragma("unroll")                                                        \
      for (int r = 0; r < s; ++r) u_[r] += u_[r + s];                          \
    ls += u_[0] + __shfl_xor(u_[0], 32);                                       \
    u32 pkv[16];                                                               \
    _Pragma("unroll")                                                          \
    for (int mf = 0; mf < 2; ++mf)                                             \
      _Pragma("unroll")                                                        \
      for (int tt = 0; tt < 8; ++tt) {                                         \
        u32 r;                                                                 \
        asm("v_cvt_pk_bf16_f32 %0, %1, %2" : "=v"(r) : "v"(ST[mf][2 * tt]), "v"(ST[mf][2 * tt + 1])); \
        pkv[mf * 8 + tt] = r;                                                  \
      }                                                                        \
    bf16x8 pfrag[4];                                                           \
    _Pragma("unroll")                                                          \
    for (int kk = 0; kk < 4; ++kk) {                                           \
      int c = (kk >> 1) * 8 + (kk & 1) * 4;                                    \
      u32 m0_ = hib ? pkv[c + 2] : pkv[c + 0];                                 \
      u32 m1_ = hib ? pkv[c + 3] : pkv[c + 1];                                 \
      u32 s0_ = hib ? pkv[c + 0] : pkv[c + 2];                                 \
      u32 s1_ = hib ? pkv[c + 1] : pkv[c + 3];                                 \
      u32 r0_ = (u32)__shfl_xor((int)s0_, 32);                                 \
      u32 r1_ = (u32)__shfl_xor((int)s1_, 32);                                 \
      u32x4 wv = {hib ? r0_ : m0_, hib ? r1_ : m1_, hib ? m0_ : r0_, hib ? m1_ : r1_}; \
      pfrag[kk] = __builtin_bit_cast(bf16x8, wv);                              \
    }                                                                          \
    const char* vb_ = (const char*)Vl + ((KT) & 1) * 16384;                    \
    _Pragma("unroll")                                                          \
    for (int mfV = 0; mfV < 4; ++mfV) {                                        \
      int row = mfV * 32 + lo5;                                                \
      const char* vr_ = vb_ + row * 128;                                       \
      int sw = (row & 7) << 4;                                                 \
      bf16x8 vf[4];                                                            \
      _Pragma("unroll")                                                        \
      for (int kk = 0; kk < 4; ++kk)                                           \
        vf[kk] = *(const bf16x8*)(vr_ + ((kk * 32 + hi * 16) ^ sw));           \
      __builtin_amdgcn_s_setprio(1);                                           \
      _Pragma("unroll")                                                        \
      for (int kk = 0; kk < 4; ++kk) ot[mfV] = mfma32(vf[kk], pfrag[kk], ot[mfV]); \
      __builtin_amdgcn_s_setprio(0);                                           \
    }                                                                          \
  }

#define ATT_BODY(P, N)                                                         \
  {                                                                            \
    asm volatile("s_waitcnt vmcnt(8)" ::: "memory");                           \
    __builtin_amdgcn_s_barrier();                                              \
    __builtin_amdgcn_sched_barrier(0);                                         \
    QKT(N, kt + 1);                                                            \
    SOFTPV(P, kt);                                                             \
    __builtin_amdgcn_s_barrier();                                              \
    {                                                                          \
      int tk_ = kt + 3 <= lastT ? kt + 3 : lastT;                              \
      int tv_ = kt + 2 <= lastT ? kt + 2 : lastT;                              \
      stageK(tk_, (kt + 3) % 3);                                               \
      stageV(tv_, kt & 1);                                                     \
    }                                                                          \
  }

__global__ __launch_bounds__(256, 2) void k_attn(const u16* __restrict__ Q, const u16* __restrict__ Kr,
                                                 const u16* __restrict__ Vt, u16* __restrict__ ctx) {
  __shared__ u16 Kl[3 * 8192];  // 48 KB: K ring, slot = 64 tokens x 128 d
  __shared__ u16 Vl[2 * 8192];  // 32 KB: V ring, slot = 128 d x 64 s
  const int id = blockIdx.x;
  const int gkv = id & 15, j = id >> 4;
  const int b = gkv >> 3, kvh = gkv & 7;
  const int h = kvh * 4 + (j & 3);
  const int p = j >> 2;
  const int bh = b * 32 + h;
  const int tid = threadIdx.x, w = tid >> 6, l = tid & 63;
  const int lo5 = l & 31, hi = l >> 5;
  const bool hib = hi != 0;
  const size_t kvslab = (size_t)(b * 8 + kvh) * 2048;
  const u16* Kg = Kr + kvslab * 128;
  const u16* Vg = Vt + kvslab * 128;  // (d, s) layout
  const float L2E = 1.4426950408889634f;

  auto stageK = [&](int kt, int slot) {
#pragma unroll
    for (int i = 0; i < 4; ++i) {
      int c = w * 4 + i;
      int sl = c * 1024 + l * 16;
      int row = sl >> 8;
      int inner = (sl & 255) ^ ((row & 15) << 4);
      g2l16((const char*)Kg + kt * 16384 + row * 256 + inner,
            (char*)Kl + slot * 16384 + c * 1024);
    }
  };
  auto stageV = [&](int kt, int slot) {
#pragma unroll
    for (int i = 0; i < 4; ++i) {
      int c = w * 4 + i;
      int sl = c * 1024 + l * 16;
      int row = sl >> 7;
      int inner = (sl & 127) ^ ((row & 7) << 4);
      g2l16((const char*)Vg + (size_t)row * 4096 + kt * 128 + inner,
            (char*)Vl + slot * 16384 + c * 1024);
    }
  };

  for (int hf = 0; hf < 2; ++hf) {
    const int qi = hf ? (15 - p) : p;
    const int q0 = qi * 128;
    const int qlane = q0 + w * 32 + lo5;
    const u16* qrow = Q + ((size_t)bh * 2048 + qlane) * 128;
    bf16x8 qf[8];
#pragma unroll
    for (int kk = 0; kk < 8; ++kk) qf[kk] = *(const bf16x8*)(qrow + kk * 16 + hi * 8);

    f32x16 ot[4];
#pragma unroll
    for (int i = 0; i < 4; ++i) ot[i] = zero16();
    float m = -1e30f, ls = 0.f;

    const int nkt = 2 * qi + 2;  // >= 2
    const int lastT = nkt - 1;

    // per-hf prologue: drain old loads, barrier (all waves done with prior LDS reads),
    // stage K0,V0,K1,V1,K2(clamped); wait oldest 8 (K0,V0); compute QK(0).
    asm volatile("s_waitcnt vmcnt(0)" ::: "memory");
    __builtin_amdgcn_s_barrier();
    stageK(0, 0); stageV(0, 0);
    stageK(1, 1); stageV(1, 1);
    stageK(2 <= lastT ? 2 : lastT, 2);
    asm volatile("s_waitcnt vmcnt(12)" ::: "memory");
    __builtin_amdgcn_s_barrier();
    __builtin_amdgcn_sched_barrier(0);
    f32x16 stA[2], stB[2];
    QKT(stA, 0);

    int kt = 0;
    for (;;) {
      ATT_BODY(stA, stB);
      if (++kt >= nkt) break;
      ATT_BODY(stB, stA);
      if (++kt >= nkt) break;
    }

    // ---- epilogue: O = (O^T)^T / ls -> ctx (b, s, h*128+d) ----
    float inv = 1.0f / ls;
    u16* crow = ctx + ((size_t)(b * 2048) + qlane) * 4096 + h * 128;
#pragma unroll
    for (int mfV = 0; mfV < 4; ++mfV)
#pragma unroll
      for (int rq = 0; rq < 4; ++rq) {
        ushort4 o4;
        o4.x = f2bf(ot[mfV][rq * 4 + 0] * inv);
        o4.y = f2bf(ot[mfV][rq * 4 + 1] * inv);
        o4.z = f2bf(ot[mfV][rq * 4 + 2] * inv);
        o4.w = f2bf(ot[mfV][rq * 4 + 3] * inv);
        *(ushort4*)(crow + mfV * 32 + rq * 8 + hi * 4) = o4;
      }
  }
}

extern "C" void kernel_launch(void* const* d_in, const int* in_sizes, int n_in,
                              void* d_out, int out_size, void* d_ws, size_t ws_size,
                              hipStream_t stream) {
  (void)in_sizes; (void)n_in; (void)out_size; (void)ws_size;
  const float* X   = (const float*)d_in[0];
  const int*   mod = (const int*)d_in[1];
  const int*   pos = (const int*)d_in[2];
  const float* Wq  = (const float*)d_in[3];
  const float* Wk0 = (const float*)d_in[4];
  const float* Wk1 = (const float*)d_in[5];
  const float* Wv0 = (const float*)d_in[6];
  const float* Wv1 = (const float*)d_in[7];
  const float* Wo  = (const float*)d_in[8];
  float* out = (float*)d_out;

  u16* p = (u16*)d_ws;
  auto take = [&](size_t n) { u16* r = p; p += n; return r; };
  u16* Xb    = take(16777216);  // X bf16 -> later ctx
  u16* WqT   = take(16777216);  // Wq^T -> later Kr | Vtr
  u16* WoT   = take(16777216);  // Wo^T
  u16* Wkv0T = take(8388608);   // [Wk0|Wv0]^T
  u16* Wkv1T = take(8388608);   // [Wk1|Wv1]^T
  u16* Qr    = take(16777216);  // (b,h,s,d)
  u16* Ksel  = take(4194304);
  u16* Vsel  = take(4194304);
  int* perm  = (int*)take(9216);
  int* meta  = (int*)take(64);
  u16* Kr  = WqT;
  u16* Vtr = WqT + 4194304;
  u16* ctx = Xb;

  k_cvt<<<dim3(16384), 256, 0, stream>>>(X, Xb, 4194304);
  k_scan<<<dim3(2), 1024, 0, stream>>>(mod, perm, meta);
  k_tcvt5<<<dim3(8192), 256, 0, stream>>>(Wq, Wk0, Wv0, Wk1, Wv1, WqT, Wkv0T, Wkv1T);

  k_gemmQKV<<<dim3(400), 1024, 0, stream>>>(Xb, WqT, Wkv0T, Wkv1T, perm, meta, Qr, Ksel, Vsel);

  k_ropekv<<<dim3(33280), 256, 0, stream>>>(Qr, Ksel, Vsel, pos, Kr, Vtr);

  k_attn<<<dim3(512), 256, 0, stream>>>(Qr, Kr, Vtr, ctx);

  k_tcvt<<<dim3(64, 64), 256, 0, stream>>>(Wo, WoT, 4096, 4096);

  k_gemm8<<<dim3(256), 512, 0, stream>>>(ctx, WoT, out);
}

// Round 14
// 540.462 us; speedup vs baseline: 1.0321x; 1.0321x over previous
//
#include <hip/hip_runtime.h>

typedef unsigned short u16;
typedef unsigned int   u32;
using bf16x8 = __attribute__((ext_vector_type(8))) __bf16;
using f32x4  = __attribute__((ext_vector_type(4))) float;
using f32x16 = __attribute__((ext_vector_type(16))) float;
using u32x4  = __attribute__((ext_vector_type(4))) unsigned int;
using ushort8 = __attribute__((ext_vector_type(8))) unsigned short;

// B=2, S=2048, D=4096, H=32, KV=8, HD=128 hardcoded throughout.

__device__ __forceinline__ u16 f2bf(float f) {
  u32 u = __builtin_bit_cast(u32, f);
  return (u16)((u + 0x7fffu + ((u >> 16) & 1u)) >> 16);
}
__device__ __forceinline__ float bf2f(u16 h) {
  return __builtin_bit_cast(float, (u32)h << 16);
}
__device__ __forceinline__ f32x4 mfma16(bf16x8 a, bf16x8 b, f32x4 c) {
  return __builtin_amdgcn_mfma_f32_16x16x32_bf16(a, b, c, 0, 0, 0);
}
__device__ __forceinline__ f32x16 mfma32(bf16x8 a, bf16x8 b, f32x16 c) {
  return __builtin_amdgcn_mfma_f32_32x32x16_bf16(a, b, c, 0, 0, 0);
}
__device__ __forceinline__ f32x16 zero16() {
  f32x16 z;
#pragma unroll
  for (int i = 0; i < 16; ++i) z[i] = 0.f;
  return z;
}
__device__ __forceinline__ void g2l16(const void* gp, void* lp) {
  __builtin_amdgcn_global_load_lds(
      (__attribute__((address_space(1))) void*)(void*)gp,
      (__attribute__((address_space(3))) void*)lp, 16, 0, 0);
}

// ---------------- fp32 -> bf16 elementwise ----------------
__global__ void k_cvt(const float* __restrict__ in, u16* __restrict__ out, int n4) {
  int i = blockIdx.x * 256 + threadIdx.x;
  if (i >= n4) return;
  float4 v = ((const float4*)in)[i];
  ushort4 o;
  o.x = f2bf(v.x); o.y = f2bf(v.y); o.z = f2bf(v.z); o.w = f2bf(v.w);
  ((ushort4*)out)[i] = o;
}

// ---------------- fp32 (K,N)->(N,K) transpose-convert, 64x64 tile core ----------------
__device__ __forceinline__ void tcvt_tile(const float* __restrict__ in, u16* __restrict__ out,
                                          int K, int N, int nt, int kt, u16 (*t)[72]) {
  const int n0 = nt * 64, k0 = kt * 64;
  const int tid = threadIdx.x;
  const int r = tid >> 2, c4 = (tid & 3) * 16;
  const float* src = in + (size_t)(k0 + r) * N + n0 + c4;
#pragma unroll
  for (int q = 0; q < 4; ++q) {
    float4 v = *(const float4*)(src + 4 * q);
    t[c4 + 4 * q + 0][r] = f2bf(v.x);
    t[c4 + 4 * q + 1][r] = f2bf(v.y);
    t[c4 + 4 * q + 2][r] = f2bf(v.z);
    t[c4 + 4 * q + 3][r] = f2bf(v.w);
  }
  __syncthreads();
  u16* dst = out + (size_t)(n0 + r) * K + k0 + c4;
#pragma unroll
  for (int hh = 0; hh < 2; ++hh)
    *(ushort8*)(dst + 8 * hh) = *(const ushort8*)(&t[r][c4 + 8 * hh]);
}

__global__ __launch_bounds__(256) void k_tcvt(const float* __restrict__ in, u16* __restrict__ out,
                                              int K, int N) {
  __shared__ u16 t[64][72];
  tcvt_tile(in, out, K, N, blockIdx.x, blockIdx.y, t);
}

__global__ __launch_bounds__(256) void k_tcvt5(const float* __restrict__ Wq, const float* __restrict__ Wk0,
                                               const float* __restrict__ Wv0, const float* __restrict__ Wk1,
                                               const float* __restrict__ Wv1, u16* __restrict__ WqT,
                                               u16* __restrict__ Wkv0T, u16* __restrict__ Wkv1T) {
  __shared__ u16 t[64][72];
  int bid = blockIdx.x;
  if (bid < 4096) {
    tcvt_tile(Wq, WqT, 4096, 4096, bid & 63, bid >> 6, t);
  } else {
    int r = bid - 4096;
    int mat = r >> 10, rr = r & 1023;
    const float* src = (mat == 0) ? Wk0 : (mat == 1) ? Wv0 : (mat == 2) ? Wk1 : Wv1;
    u16* dst = (mat == 0) ? Wkv0T : (mat == 1) ? (Wkv0T + (size_t)1024 * 4096)
                                  : (mat == 2) ? Wkv1T : (Wkv1T + (size_t)1024 * 4096);
    tcvt_tile(src, dst, 4096, 1024, rr & 15, rr >> 4, t);
  }
}

// ---------------- modality scan ----------------
__global__ void k_scan(const int* __restrict__ mod, int* __restrict__ perm, int* __restrict__ meta) {
  __shared__ int ps[1024];
  const int b = blockIdx.x, t = threadIdx.x;
  perm[b * 2304 + t] = -1;
  perm[b * 2304 + 1024 + t] = -1;
  if (t < 256) perm[b * 2304 + 2048 + t] = -1;
  const int i0 = 2 * t, i1 = 2 * t + 1;
  const int f0 = (mod[b * 2048 + i0] != 1) ? 1 : 0;
  const int f1 = (mod[b * 2048 + i1] != 1) ? 1 : 0;
  const int sum = f0 + f1;
  ps[t] = sum;
  __syncthreads();
  for (int off = 1; off < 1024; off <<= 1) {
    int v = (t >= off) ? ps[t - off] : 0;
    __syncthreads();
    ps[t] += v;
    __syncthreads();
  }
  const int total0 = ps[1023];
  const int excl = ps[t] - sum;
  const int nt0 = (total0 + 255) >> 8;
  const int off1 = nt0 * 256;
  const int s0 = f0 ? excl : off1 + (i0 - excl);
  const int s1 = f1 ? (excl + f0) : off1 + (i1 - (excl + f0));
  perm[b * 2304 + s0] = i0;
  perm[b * 2304 + s1] = i1;
  if (t == 0) { meta[b * 2] = total0; meta[b * 2 + 1] = nt0; }
}

// ================= 8-phase 256x256 bf16 GEMM core (K=4096), 512 thr (for k_gemm8) ==========
#define BARSB() { __builtin_amdgcn_s_barrier(); __builtin_amdgcn_sched_barrier(0); }
#define VMC(N)  asm volatile("s_waitcnt vmcnt(" #N ")" ::: "memory")

#define READ_A(MH, SL) { _Pragma("unroll") for (int mf_ = 0; mf_ < 4; ++mf_) {       \
    const char* a_ = (const char*)lds8 + (SL)*65536 + (MH)*16384 + (arow + mf_*16)*128; \
    afr[mf_][0] = *(const bf16x8*)(a_ + swc0);                                        \
    afr[mf_][1] = *(const bf16x8*)(a_ + swc1); } }

#define READ_B(NH, SL) { _Pragma("unroll") for (int nf_ = 0; nf_ < 2; ++nf_) {       \
    const char* b_ = (const char*)lds8 + (SL)*65536 + 32768 + (NH)*16384 + (brow + nf_*16)*128; \
    bfr[nf_][0] = *(const bf16x8*)(b_ + swc0);                                        \
    bfr[nf_][1] = *(const bf16x8*)(b_ + swc1); } }

#define MM16(MH, NH) { __builtin_amdgcn_s_setprio(1);                                 \
  _Pragma("unroll") for (int mf_ = 0; mf_ < 4; ++mf_)                                 \
    _Pragma("unroll") for (int nf_ = 0; nf_ < 2; ++nf_) {                             \
      acc[MH][mf_][NH][nf_] = mfma16(afr[mf_][0], bfr[nf_][0], acc[MH][mf_][NH][nf_]); \
      acc[MH][mf_][NH][nf_] = mfma16(afr[mf_][1], bfr[nf_][1], acc[MH][mf_][NH][nf_]); } \
  __builtin_amdgcn_s_setprio(0); }

#define STAGE_A(T, MH) { int ts_ = (T) < 64 ? (T) : 63;                               \
    char* d_ = (char*)lds8 + ((T)&1)*65536 + (MH)*16384 + wid*1024;                   \
    g2l16(pA0[MH] + ts_*64, d_); g2l16(pA1[MH] + ts_*64, d_ + 8192); }

#define STAGE_B(T, NH) { int ts_ = (T) < 64 ? (T) : 63;                               \
    char* d_ = (char*)lds8 + ((T)&1)*65536 + 32768 + (NH)*16384 + wid*1024;           \
    g2l16(pB0[NH] + ts_*64, d_); g2l16(pB1[NH] + ts_*64, d_ + 8192); }

#define G8_MAINLOOP()                                                                 \
  STAGE_A(0,0); STAGE_B(0,1); STAGE_A(0,1); STAGE_B(0,0);                             \
  STAGE_A(1,0); STAGE_B(1,1); STAGE_A(1,1);                                           \
  VMC(6); BARSB();                                                                    \
  for (int i_ = 0; i_ < 32; ++i_) {                                                   \
    const int ta_ = 2 * i_;                                                           \
    READ_A(0,0); READ_B(0,0); STAGE_B(ta_+1, 0); BARSB(); MM16(0,0); BARSB();         \
    READ_B(1,0);              STAGE_A(ta_+2, 0); BARSB(); MM16(0,1); BARSB();         \
    READ_A(1,0);              STAGE_B(ta_+2, 1); BARSB(); MM16(1,1); BARSB();         \
    READ_B(0,0);              STAGE_A(ta_+2, 1); BARSB(); MM16(1,0); VMC(4); BARSB(); \
    READ_A(0,1); READ_B(0,1); STAGE_B(ta_+2, 0); BARSB(); MM16(0,0); BARSB();         \
    READ_B(1,1);              STAGE_A(ta_+3, 0); BARSB(); MM16(0,1); BARSB();         \
    READ_A(1,1);              STAGE_B(ta_+3, 1); BARSB(); MM16(1,1); BARSB();         \
    READ_B(0,1);              STAGE_A(ta_+3, 1); BARSB(); MM16(1,0); VMC(4); BARSB(); \
  }

// ---- O-projection GEMM: fp32 row-major out (8-phase core) ----
__global__ __launch_bounds__(512, 2) void k_gemm8(const u16* __restrict__ A, const u16* __restrict__ Bt,
                                                  float* __restrict__ Cp) {
  __shared__ u16 lds8[65536];  // 128 KB
  const int tid = threadIdx.x, wid = tid >> 6, l = tid & 63, g = l >> 4, li = l & 15;
  const int wr = wid >> 2, wc = wid & 3;
  const int bid = blockIdx.x;
  const int swz = (bid & 7) * 32 + (bid >> 3);
  const int m0 = (swz >> 4) * 256, n0 = (swz & 15) * 256;

  const int swc0 = (g * 16) ^ ((li & 7) << 4);
  const int swc1 = (64 + g * 16) ^ ((li & 7) << 4);
  const int arow = wr * 64 + li;
  const int brow = wc * 32 + li;

  const int l8a = tid * 16, l8b = 8192 + tid * 16;
  const int oa = l8a ^ (((l8a >> 7) & 7) << 4), ob = l8b ^ (((l8b >> 7) & 7) << 4);
  const int rl0 = oa >> 7, cb0 = oa & 127, rl1 = ob >> 7, cb1 = ob & 127;
  const int RA0 = (rl0 >> 6) * 128 + (rl0 & 63), RA1 = (rl1 >> 6) * 128 + (rl1 & 63);
  const int CB0 = (rl0 >> 5) * 64 + (rl0 & 31), CB1 = (rl1 >> 5) * 64 + (rl1 & 31);
  const u16 *pA0[2], *pA1[2], *pB0[2], *pB1[2];
#pragma unroll
  for (int mh = 0; mh < 2; ++mh) {
    pA0[mh] = A + (size_t)(m0 + RA0 + mh * 64) * 4096 + cb0 / 2;
    pA1[mh] = A + (size_t)(m0 + RA1 + mh * 64) * 4096 + cb1 / 2;
    pB0[mh] = Bt + (size_t)(n0 + CB0 + mh * 32) * 4096 + cb0 / 2;
    pB1[mh] = Bt + (size_t)(n0 + CB1 + mh * 32) * 4096 + cb1 / 2;
  }

  bf16x8 afr[4][2], bfr[2][2];
  const f32x4 vzero = {0.f, 0.f, 0.f, 0.f};
  f32x4 acc[2][4][2][2];
#pragma unroll
  for (int a = 0; a < 2; ++a)
#pragma unroll
    for (int b = 0; b < 4; ++b)
#pragma unroll
      for (int c = 0; c < 2; ++c)
#pragma unroll
        for (int d = 0; d < 2; ++d) acc[a][b][c][d] = vzero;

  G8_MAINLOOP();

#pragma unroll
  for (int mh = 0; mh < 2; ++mh)
#pragma unroll
    for (int mf = 0; mf < 4; ++mf)
#pragma unroll
      for (int nh = 0; nh < 2; ++nh)
#pragma unroll
        for (int nf = 0; nf < 2; ++nf)
#pragma unroll
          for (int j = 0; j < 4; ++j) {
            int row = m0 + wr * 128 + mh * 64 + mf * 16 + g * 4 + j;
            int col = n0 + wc * 64 + nh * 32 + nf * 16 + li;
            Cp[(size_t)row * 4096 + col] = acc[mh][mf][nh][nf][j];
          }
}

// ================= r9 16-wave GEMM core (1024 thr, 4-slot, vmcnt4) for QKV ==================
#define TB16(T, VMLIT, DOSTAGE)                                              \
  {                                                                          \
    asm volatile("s_waitcnt vmcnt(" VMLIT ")" ::: "memory");                 \
    __builtin_amdgcn_s_barrier();                                            \
    __builtin_amdgcn_sched_barrier(0);                                       \
    const u16* base_ = lds + ((T) & 3) * 16384;                              \
    bf16x8 bfr[4], afr[4];                                                   \
    _Pragma("unroll")                                                        \
    for (int nf = 0; nf < 4; ++nf)                                           \
      bfr[nf] = *(const bf16x8*)(base_ + boff + nf * 512);                   \
    _Pragma("unroll")                                                        \
    for (int mf = 0; mf < 4; ++mf)                                           \
      afr[mf] = *(const bf16x8*)(base_ + aoff + mf * 512);                   \
    if (DOSTAGE) stage((T) + 3);                                             \
    __builtin_amdgcn_s_setprio(1);                                           \
    _Pragma("unroll")                                                        \
    for (int mf = 0; mf < 4; ++mf)                                           \
      _Pragma("unroll")                                                      \
      for (int nf = 0; nf < 4; ++nf)                                         \
        acc[mf][nf] = mfma16(afr[mf], bfr[nf], acc[mf][nf]);                 \
    __builtin_amdgcn_s_setprio(0);                                           \
  }

#define LOOP16()                                                             \
  stage(0); stage(1); stage(2);                                              \
  for (int t = 0; t < 125; ++t) TB16(t, "4", true);                          \
  TB16(125, "4", false);                                                     \
  TB16(126, "2", false);                                                     \
  TB16(127, "0", false);

// ---- merged Q + segmented-KV GEMM, 400 blocks, 1024 thr (r9 core) ----
__global__ __launch_bounds__(1024, 4) void k_gemmQKV(const u16* __restrict__ Xb, const u16* __restrict__ WqT,
                                                     const u16* __restrict__ B0, const u16* __restrict__ B1,
                                                     const int* __restrict__ perm, const int* __restrict__ meta,
                                                     u16* __restrict__ Qr, u16* __restrict__ Ksel,
                                                     u16* __restrict__ Vsel) {
  __shared__ u16 lds[4 * 16384];
  const int tid = threadIdx.x, wid = tid >> 6, l = tid & 63, g = l >> 4, li = l & 15;
  const int wr = wid >> 2, wc = wid & 3;
  const int bid = blockIdx.x;
  const bool isQ = bid < 256;

  const int srow = wid * 16 + (l >> 2);
  const int sgg = (l & 3) ^ ((l >> 3) & 3);

  int m0 = 0, n0 = 0, bb = 0, tm = 0;
  const u16 *pA, *pB;
  if (isQ) {
    const int swz = (bid & 7) * 32 + (bid >> 3);
    m0 = (swz >> 4) * 256; n0 = (swz & 15) * 256;
    pA = Xb + (size_t)(m0 + srow) * 4096 + sgg * 8;
    pB = WqT + (size_t)(n0 + srow) * 4096 + sgg * 8;
  } else {
    const int kb = bid - 256;
    const int seg = kb >> 3;
    n0 = (kb & 7) * 256;
    bb = seg / 9; tm = seg % 9;
    const int nt0 = meta[bb * 2 + 1];
    const u16* Bt = (tm >= nt0) ? B1 : B0;
    int t0 = perm[bb * 2304 + tm * 256 + srow];
    if (t0 < 0) t0 = 0;
    pA = Xb + ((size_t)bb * 2048 + t0) * 4096 + sgg * 8;
    pB = Bt + (size_t)(n0 + srow) * 4096 + sgg * 8;
  }

  auto stage = [&](int t) {
    u16* da = (u16*)lds + (t & 3) * 16384 + wid * 512;
    g2l16(pA + t * 32, da);
    g2l16(pB + t * 32, da + 8192);
  };

  const int lsl8 = (g ^ ((li >> 1) & 3)) * 8;
  const int aoff = (wr * 64 + li) * 32 + lsl8;
  const int boff = 8192 + (wc * 64 + li) * 32 + lsl8;

  const f32x4 vzero = {0.f, 0.f, 0.f, 0.f};
  f32x4 acc[4][4];
#pragma unroll
  for (int m = 0; m < 4; ++m)
#pragma unroll
    for (int n = 0; n < 4; ++n) acc[m][n] = vzero;

  LOOP16();

  if (isQ) {
#pragma unroll
    for (int mf = 0; mf < 4; ++mf)
#pragma unroll
      for (int nf = 0; nf < 4; ++nf)
#pragma unroll
        for (int j = 0; j < 4; ++j) {
          int row = m0 + wr * 64 + mf * 16 + g * 4 + j;
          int col = n0 + wc * 64 + nf * 16 + li;
          int b = row >> 11, s = row & 2047, h = col >> 7, d = col & 127;
          Qr[(((size_t)(b * 32 + h)) * 2048 + s) * 128 + d] = f2bf(acc[mf][nf][j]);
        }
  } else {
#pragma unroll
    for (int mf = 0; mf < 4; ++mf)
#pragma unroll
      for (int nf = 0; nf < 4; ++nf)
#pragma unroll
        for (int j = 0; j < 4; ++j) {
          int slot = tm * 256 + wr * 64 + mf * 16 + g * 4 + j;
          int tok = perm[bb * 2304 + slot];
          if (tok >= 0) {
            int col = n0 + wc * 64 + nf * 16 + li;   // 0..2047
            int kv = col >> 10, hh = (col >> 7) & 7, d = col & 127;
            u16* dst = (kv ? Vsel : Ksel) + (((size_t)(bb * 8 + hh)) * 2048 + tok) * 128 + d;
            *dst = f2bf(acc[mf][nf][j]);
          }
        }
  }
}

// ---------------- merged: RoPE(Q) + [RoPE(K) + V transpose] ----------------
__global__ __launch_bounds__(256) void k_ropekv(u16* __restrict__ Q, const u16* __restrict__ Ks,
                                                const u16* __restrict__ Vs, const int* __restrict__ pos,
                                                u16* __restrict__ Kr, u16* __restrict__ Vt) {
  __shared__ u16 Vl[64][136];
  const int bid = blockIdx.x;
  const int tid = threadIdx.x, l = tid & 63;
  const float invf = expf((float)l * -0.14391156831212787f);
  if (bid < 32768) {
    int row = bid * 4 + (tid >> 6);
    int s = row & 2047;
    u16* p = Q + (size_t)row * 128;
    float x1 = bf2f(p[l]), x2 = bf2f(p[l + 64]);
    float ang = (float)pos[s] * invf;
    float cs = cosf(ang), sn = sinf(ang);
    const float sc = 0.08838834764831845f;
    p[l] = f2bf((x1 * cs - x2 * sn) * sc);
    p[l + 64] = f2bf((x2 * cs + x1 * sn) * sc);
  } else {
    int blk = bid - 32768;
    int st = blk & 31, kvh = (blk >> 5) & 7, b = blk >> 8;
    int s0 = st * 64;
    int wid = tid >> 6;
    size_t slab = (size_t)(b * 8 + kvh) * 2048;
    for (int rr = 0; rr < 16; ++rr) {
      int r = wid * 16 + rr;
      int s = s0 + r;
      const u16* ks = Ks + (slab + s) * 128;
      const u16* vs = Vs + (slab + s) * 128;
      float ang = (float)pos[s] * invf;
      float cs = cosf(ang), sn = sinf(ang);
      float x1 = bf2f(ks[l]), x2 = bf2f(ks[l + 64]);
      u16* kd = Kr + (slab + s) * 128;
      kd[l] = f2bf(x1 * cs - x2 * sn);
      kd[l + 64] = f2bf(x2 * cs + x1 * sn);
      Vl[r][l] = vs[l];
      Vl[r][l + 64] = vs[l + 64];
    }
    __syncthreads();
    int d = tid >> 1, si0 = (tid & 1) * 32;
    u16* vd = Vt + ((size_t)(b * 8 + kvh) * 128 + d) * 2048 + s0 + si0;
#pragma unroll
    for (int k4 = 0; k4 < 8; ++k4) {
      ushort4 o;
      o.x = Vl[si0 + k4 * 4 + 0][d];
      o.y = Vl[si0 + k4 * 4 + 1][d];
      o.z = Vl[si0 + k4 * 4 + 2][d];
      o.w = Vl[si0 + k4 * 4 + 3][d];
      *(ushort4*)(vd + k4 * 4) = o;
    }
  }
}

// ---------------- causal GQA flash attention: counted-vmcnt + XCD-affinity (r12 proven) ----------------
__global__ __launch_bounds__(256, 2) void k_attn(const u16* __restrict__ Q, const u16* __restrict__ Kr,
                                                 const u16* __restrict__ Vt, u16* __restrict__ ctx) {
  __shared__ u16 Kl[2 * 64 * 128];
  __shared__ u16 Vl[2 * 128 * 64];
  const int id = blockIdx.x;
  const int gkv = id & 15, j = id >> 4;
  const int b = gkv >> 3, kvh = gkv & 7;
  const int h = kvh * 4 + (j & 3);
  const int p = j >> 2;
  const int bh = b * 32 + h;
  const int tid = threadIdx.x, w = tid >> 6, l = tid & 63;
  const int lo5 = l & 31, hi = l >> 5;
  const bool hib = hi != 0;
  const size_t kvslab = (size_t)(b * 8 + kvh) * 2048;
  const u16* Kg = Kr + kvslab * 128;
  const u16* Vg = Vt + kvslab * 128;  // (d, s) layout
  const float L2E = 1.4426950408889634f;

  auto stage = [&](int kt, int bi) {
#pragma unroll
    for (int i = 0; i < 4; ++i) {
      int c = w * 4 + i;
      int slot = c * 1024 + l * 16;
      {  // K tile: 64 rows x 256B, 16-slot xor swizzle
        int row = slot >> 8;
        int inner = (slot & 255) ^ ((row & 15) << 4);
        g2l16((const char*)Kg + kt * 16384 + row * 256 + inner,
              (char*)Kl + bi * 16384 + c * 1024);
      }
      {  // V tile: 128 rows (d) x 128B, 8-slot swizzle
        int row = slot >> 7;
        int inner = (slot & 127) ^ ((row & 7) << 4);
        g2l16((const char*)Vg + (size_t)row * 4096 + kt * 128 + inner,
              (char*)Vl + bi * 16384 + c * 1024);
      }
    }
  };

  for (int hf = 0; hf < 2; ++hf) {
    const int qi = hf ? (15 - p) : p;
    const int q0 = qi * 128;
    const int qlane = q0 + w * 32 + lo5;
    const u16* qrow = Q + ((size_t)bh * 2048 + qlane) * 128;
    bf16x8 qf[8];
#pragma unroll
    for (int kk = 0; kk < 8; ++kk) qf[kk] = *(const bf16x8*)(qrow + kk * 16 + hi * 8);

    f32x16 ot[4];
#pragma unroll
    for (int i = 0; i < 4; ++i) ot[i] = zero16();
    float m = -1e30f, ls = 0.f;

    const int nkt = 2 * qi + 2;  // >= 2
    stage(0, 0);
    stage(1, 1);
    for (int kt = 0; kt < nkt; ++kt) {
      if (kt + 1 < nkt) {
        asm volatile("s_waitcnt vmcnt(8)" ::: "memory");
      } else {
        asm volatile("s_waitcnt vmcnt(0)" ::: "memory");
      }
      __builtin_amdgcn_s_barrier();
      __builtin_amdgcn_sched_barrier(0);
      const char* kbase = (const char*)Kl + (kt & 1) * 16384;
      const char* vbase = (const char*)Vl + (kt & 1) * 16384;
      const int ktb = kt * 64;
      if (ktb <= q0 + w * 32 + 31) {  // wave-uniform active check
        // ---- QK^T swapped: st[mf] = S^T[k=mf*32+..][q] ----
        f32x16 st[2];
        st[0] = zero16(); st[1] = zero16();
#pragma unroll
        for (int kk = 0; kk < 8; ++kk) {
          bf16x8 kfr[2];
#pragma unroll
          for (int mf = 0; mf < 2; ++mf) {
            int row = mf * 32 + lo5;
            kfr[mf] = *(const bf16x8*)(kbase + row * 256 + ((kk * 32 + hi * 16) ^ ((row & 15) << 4)));
          }
          __builtin_amdgcn_s_setprio(1);
          st[0] = mfma32(kfr[0], qf[kk], st[0]);
          st[1] = mfma32(kfr[1], qf[kk], st[1]);
          __builtin_amdgcn_s_setprio(0);
        }
        // ---- causal mask (boundary tiles only) ----
        if (ktb + 63 > q0 + w * 32) {
#pragma unroll
          for (int mf = 0; mf < 2; ++mf)
#pragma unroll
            for (int r = 0; r < 16; ++r) {
              int kg = ktb + mf * 32 + (r & 3) + 8 * (r >> 2) + 4 * hi;
              if (kg > qlane) st[mf][r] = -3.0e38f;
            }
        }
        // ---- online softmax, fully in-register ----
        float t[16];
#pragma unroll
        for (int r = 0; r < 16; ++r) t[r] = fmaxf(st[0][r], st[1][r]);
#pragma unroll
        for (int s = 8; s >= 1; s >>= 1)
#pragma unroll
          for (int r = 0; r < s; ++r) t[r] = fmaxf(t[r], t[r + s]);
        float pmax = fmaxf(t[0], __shfl_xor(t[0], 32));
        if (!__all(pmax <= m + 8.f)) {  // T13 defer-max
          float nm = fmaxf(m, pmax);
          float resc = exp2f((m - nm) * L2E);
          m = nm;
          ls *= resc;
#pragma unroll
          for (int i = 0; i < 4; ++i)
#pragma unroll
            for (int r = 0; r < 16; ++r) ot[i][r] *= resc;
        }
#pragma unroll
        for (int mf = 0; mf < 2; ++mf)
#pragma unroll
          for (int r = 0; r < 16; ++r) st[mf][r] = exp2f((st[mf][r] - m) * L2E);
        float u[16];
#pragma unroll
        for (int r = 0; r < 16; ++r) u[r] = st[0][r] + st[1][r];
#pragma unroll
        for (int s = 8; s >= 1; s >>= 1)
#pragma unroll
          for (int r = 0; r < s; ++r) u[r] += u[r + s];
        ls += u[0] + __shfl_xor(u[0], 32);
        // ---- pack P^T -> bf16 B-frags (T12) ----
        u32 pkv[16];
#pragma unroll
        for (int mf = 0; mf < 2; ++mf)
#pragma unroll
          for (int tt = 0; tt < 8; ++tt) {
            u32 r;
            asm("v_cvt_pk_bf16_f32 %0, %1, %2" : "=v"(r) : "v"(st[mf][2 * tt]), "v"(st[mf][2 * tt + 1]));
            pkv[mf * 8 + tt] = r;
          }
        bf16x8 pfrag[4];
#pragma unroll
        for (int kk = 0; kk < 4; ++kk) {
          int c = (kk >> 1) * 8 + (kk & 1) * 4;
          u32 m0 = hib ? pkv[c + 2] : pkv[c + 0];
          u32 m1 = hib ? pkv[c + 3] : pkv[c + 1];
          u32 s0 = hib ? pkv[c + 0] : pkv[c + 2];
          u32 s1 = hib ? pkv[c + 1] : pkv[c + 3];
          u32 r0 = (u32)__shfl_xor((int)s0, 32);
          u32 r1 = (u32)__shfl_xor((int)s1, 32);
          u32x4 wv = {hib ? r0 : m0, hib ? r1 : m1, hib ? m0 : r0, hib ? m1 : r1};
          pfrag[kk] = __builtin_bit_cast(bf16x8, wv);
        }
        // ---- PV swapped ----
#pragma unroll
        for (int mfV = 0; mfV < 4; ++mfV) {
          int row = mfV * 32 + lo5;
          const char* vb = vbase + row * 128;
          int sw = (row & 7) << 4;
          bf16x8 vf[4];
#pragma unroll
          for (int kk = 0; kk < 4; ++kk)
            vf[kk] = *(const bf16x8*)(vb + ((kk * 32 + hi * 16) ^ sw));
          __builtin_amdgcn_s_setprio(1);
#pragma unroll
          for (int kk = 0; kk < 4; ++kk) ot[mfV] = mfma32(vf[kk], pfrag[kk], ot[mfV]);
          __builtin_amdgcn_s_setprio(0);
        }
      }
      __builtin_amdgcn_s_barrier();
      if (kt + 2 < nkt) stage(kt + 2, kt & 1);
    }
    // ---- epilogue ----
    float inv = 1.0f / ls;
    u16* crow = ctx + ((size_t)(b * 2048) + qlane) * 4096 + h * 128;
#pragma unroll
    for (int mfV = 0; mfV < 4; ++mfV)
#pragma unroll
      for (int rq = 0; rq < 4; ++rq) {
        ushort4 o4;
        o4.x = f2bf(ot[mfV][rq * 4 + 0] * inv);
        o4.y = f2bf(ot[mfV][rq * 4 + 1] * inv);
        o4.z = f2bf(ot[mfV][rq * 4 + 2] * inv);
        o4.w = f2bf(ot[mfV][rq * 4 + 3] * inv);
        *(ushort4*)(crow + mfV * 32 + rq * 8 + hi * 4) = o4;
      }
  }
}

extern "C" void kernel_launch(void* const* d_in, const int* in_sizes, int n_in,
                              void* d_out, int out_size, void* d_ws, size_t ws_size,
                              hipStream_t stream) {
  (void)in_sizes; (void)n_in; (void)out_size; (void)ws_size;
  const float* X   = (const float*)d_in[0];
  const int*   mod = (const int*)d_in[1];
  const int*   pos = (const int*)d_in[2];
  const float* Wq  = (const float*)d_in[3];
  const float* Wk0 = (const float*)d_in[4];
  const float* Wk1 = (const float*)d_in[5];
  const float* Wv0 = (const float*)d_in[6];
  const float* Wv1 = (const float*)d_in[7];
  const float* Wo  = (const float*)d_in[8];
  float* out = (float*)d_out;

  u16* p = (u16*)d_ws;
  auto take = [&](size_t n) { u16* r = p; p += n; return r; };
  u16* Xb    = take(16777216);  // X bf16 -> later ctx
  u16* WqT   = take(16777216);  // Wq^T -> later Kr | Vtr
  u16* WoT   = take(16777216);  // Wo^T
  u16* Wkv0T = take(8388608);   // [Wk0|Wv0]^T
  u16* Wkv1T = take(8388608);   // [Wk1|Wv1]^T
  u16* Qr    = take(16777216);  // (b,h,s,d)
  u16* Ksel  = take(4194304);
  u16* Vsel  = take(4194304);
  int* perm  = (int*)take(9216);
  int* meta  = (int*)take(64);
  u16* Kr  = WqT;
  u16* Vtr = WqT + 4194304;
  u16* ctx = Xb;

  k_cvt<<<dim3(16384), 256, 0, stream>>>(X, Xb, 4194304);
  k_scan<<<dim3(2), 1024, 0, stream>>>(mod, perm, meta);
  k_tcvt5<<<dim3(8192), 256, 0, stream>>>(Wq, Wk0, Wv0, Wk1, Wv1, WqT, Wkv0T, Wkv1T);

  k_gemmQKV<<<dim3(400), 1024, 0, stream>>>(Xb, WqT, Wkv0T, Wkv1T, perm, meta, Qr, Ksel, Vsel);

  k_ropekv<<<dim3(33280), 256, 0, stream>>>(Qr, Ksel, Vsel, pos, Kr, Vtr);

  k_attn<<<dim3(512), 256, 0, stream>>>(Qr, Kr, Vtr, ctx);

  k_tcvt<<<dim3(64, 64), 256, 0, stream>>>(Wo, WoT, 4096, 4096);

  k_gemm8<<<dim3(256), 512, 0, stream>>>(ctx, WoT, out);
}

// Round 15
// 515.605 us; speedup vs baseline: 1.0818x; 1.0482x over previous
//
#include <hip/hip_runtime.h>

typedef unsigned short u16;
typedef unsigned int   u32;
using bf16x8 = __attribute__((ext_vector_type(8))) __bf16;
using f32x4  = __attribute__((ext_vector_type(4))) float;
using f32x16 = __attribute__((ext_vector_type(16))) float;
using u32x4  = __attribute__((ext_vector_type(4))) unsigned int;
using ushort8 = __attribute__((ext_vector_type(8))) unsigned short;

// B=2, S=2048, D=4096, H=32, KV=8, HD=128 hardcoded throughout.

__device__ __forceinline__ u16 f2bf(float f) {
  u32 u = __builtin_bit_cast(u32, f);
  return (u16)((u + 0x7fffu + ((u >> 16) & 1u)) >> 16);
}
__device__ __forceinline__ float bf2f(u16 h) {
  return __builtin_bit_cast(float, (u32)h << 16);
}
__device__ __forceinline__ f32x4 mfma16(bf16x8 a, bf16x8 b, f32x4 c) {
  return __builtin_amdgcn_mfma_f32_16x16x32_bf16(a, b, c, 0, 0, 0);
}
__device__ __forceinline__ f32x16 mfma32(bf16x8 a, bf16x8 b, f32x16 c) {
  return __builtin_amdgcn_mfma_f32_32x32x16_bf16(a, b, c, 0, 0, 0);
}
__device__ __forceinline__ f32x16 zero16() {
  f32x16 z;
#pragma unroll
  for (int i = 0; i < 16; ++i) z[i] = 0.f;
  return z;
}
__device__ __forceinline__ void g2l16(const void* gp, void* lp) {
  __builtin_amdgcn_global_load_lds(
      (__attribute__((address_space(1))) void*)(void*)gp,
      (__attribute__((address_space(3))) void*)lp, 16, 0, 0);
}

// ---------------- fp32 (K,N)->(N,K) transpose-convert, 64x64 tile core ----------------
__device__ __forceinline__ void tcvt_tile(const float* __restrict__ in, u16* __restrict__ out,
                                          int K, int N, int nt, int kt, u16 (*t)[72]) {
  const int n0 = nt * 64, k0 = kt * 64;
  const int tid = threadIdx.x;
  const int r = tid >> 2, c4 = (tid & 3) * 16;
  const float* src = in + (size_t)(k0 + r) * N + n0 + c4;
#pragma unroll
  for (int q = 0; q < 4; ++q) {
    float4 v = *(const float4*)(src + 4 * q);
    t[c4 + 4 * q + 0][r] = f2bf(v.x);
    t[c4 + 4 * q + 1][r] = f2bf(v.y);
    t[c4 + 4 * q + 2][r] = f2bf(v.z);
    t[c4 + 4 * q + 3][r] = f2bf(v.w);
  }
  __syncthreads();
  u16* dst = out + (size_t)(n0 + r) * K + k0 + c4;
#pragma unroll
  for (int hh = 0; hh < 2; ++hh)
    *(ushort8*)(dst + 8 * hh) = *(const ushort8*)(&t[r][c4 + 8 * hh]);
}

// ================ merged prep: cvt + 5-way Wt + Wo^T + sincos table + scan ================
// bid ranges: [0,16384) X cvt | [16384,24576) Wq/Wk/Wv transpose | [24576,28672) Wo^T
//             [28672,29184) sincos table | [29184,29186) modality scan
__global__ __launch_bounds__(256) void k_prep(const float* __restrict__ X,
                                              const float* __restrict__ Wq, const float* __restrict__ Wk0,
                                              const float* __restrict__ Wv0, const float* __restrict__ Wk1,
                                              const float* __restrict__ Wv1, const float* __restrict__ Wo,
                                              const int* __restrict__ mod, const int* __restrict__ pos,
                                              u16* __restrict__ Xb, u16* __restrict__ WqT,
                                              u16* __restrict__ Wkv0T, u16* __restrict__ Wkv1T,
                                              u16* __restrict__ WoT, float2* __restrict__ tab,
                                              int* __restrict__ perm, int* __restrict__ meta) {
  __shared__ u16 t[64][72];
  __shared__ int ps[256];
  const int bid = blockIdx.x, tid = threadIdx.x;
  if (bid < 16384) {
    int i = bid * 256 + tid;
    float4 v = ((const float4*)X)[i];
    ushort4 o;
    o.x = f2bf(v.x); o.y = f2bf(v.y); o.z = f2bf(v.z); o.w = f2bf(v.w);
    ((ushort4*)Xb)[i] = o;
  } else if (bid < 24576) {
    int r = bid - 16384;
    if (r < 4096) {
      tcvt_tile(Wq, WqT, 4096, 4096, r & 63, r >> 6, t);
    } else {
      r -= 4096;
      int mat = r >> 10, rr = r & 1023;
      const float* src = (mat == 0) ? Wk0 : (mat == 1) ? Wv0 : (mat == 2) ? Wk1 : Wv1;
      u16* dst = (mat == 0) ? Wkv0T : (mat == 1) ? (Wkv0T + (size_t)1024 * 4096)
                                    : (mat == 2) ? Wkv1T : (Wkv1T + (size_t)1024 * 4096);
      tcvt_tile(src, dst, 4096, 1024, rr & 15, rr >> 4, t);
    }
  } else if (bid < 28672) {
    int r = bid - 24576;
    tcvt_tile(Wo, WoT, 4096, 4096, r & 63, r >> 6, t);
  } else if (bid < 29184) {
    int idx = (bid - 28672) * 256 + tid;  // [0, 131072)
    int s = idx >> 6, f = idx & 63;
    float ang = (float)pos[s] * expf((float)f * -0.14391156831212787f);  // ln(1e4)/64
    tab[idx] = make_float2(cosf(ang), sinf(ang));
  } else {
    // modality scan at 256 thr: per-batch stable partition into 256-padded segments
    const int b = bid - 29184;
#pragma unroll
    for (int i = 0; i < 9; ++i) perm[b * 2304 + i * 256 + tid] = -1;
    int f[8], loc = 0;
#pragma unroll
    for (int i = 0; i < 8; ++i) {
      f[i] = (mod[b * 2048 + tid * 8 + i] != 1) ? 1 : 0;
      loc += f[i];
    }
    ps[tid] = loc;
    __syncthreads();
    for (int off = 1; off < 256; off <<= 1) {
      int v = (tid >= off) ? ps[tid - off] : 0;
      __syncthreads();
      ps[tid] += v;
      __syncthreads();
    }
    const int total0 = ps[255];
    int c0 = ps[tid] - loc;  // mod0 tokens before token tid*8
    const int nt0 = (total0 + 255) >> 8;
    const int off1 = nt0 * 256;
#pragma unroll
    for (int i = 0; i < 8; ++i) {
      int idx = tid * 8 + i;
      if (f[i]) {
        perm[b * 2304 + c0] = idx;
        ++c0;
      } else {
        perm[b * 2304 + off1 + idx - c0] = idx;
      }
    }
    if (tid == 0) { meta[b * 2] = total0; meta[b * 2 + 1] = nt0; }
  }
}

// ================= 8-phase 256x256 bf16 GEMM core (K=4096), 512 thr (for k_gemm8) ==========
#define BARSB() { __builtin_amdgcn_s_barrier(); __builtin_amdgcn_sched_barrier(0); }
#define VMC(N)  asm volatile("s_waitcnt vmcnt(" #N ")" ::: "memory")

#define READ_A(MH, SL) { _Pragma("unroll") for (int mf_ = 0; mf_ < 4; ++mf_) {       \
    const char* a_ = (const char*)lds8 + (SL)*65536 + (MH)*16384 + (arow + mf_*16)*128; \
    afr[mf_][0] = *(const bf16x8*)(a_ + swc0);                                        \
    afr[mf_][1] = *(const bf16x8*)(a_ + swc1); } }

#define READ_B(NH, SL) { _Pragma("unroll") for (int nf_ = 0; nf_ < 2; ++nf_) {       \
    const char* b_ = (const char*)lds8 + (SL)*65536 + 32768 + (NH)*16384 + (brow + nf_*16)*128; \
    bfr[nf_][0] = *(const bf16x8*)(b_ + swc0);                                        \
    bfr[nf_][1] = *(const bf16x8*)(b_ + swc1); } }

#define MM16(MH, NH) { __builtin_amdgcn_s_setprio(1);                                 \
  _Pragma("unroll") for (int mf_ = 0; mf_ < 4; ++mf_)                                 \
    _Pragma("unroll") for (int nf_ = 0; nf_ < 2; ++nf_) {                             \
      acc[MH][mf_][NH][nf_] = mfma16(afr[mf_][0], bfr[nf_][0], acc[MH][mf_][NH][nf_]); \
      acc[MH][mf_][NH][nf_] = mfma16(afr[mf_][1], bfr[nf_][1], acc[MH][mf_][NH][nf_]); } \
  __builtin_amdgcn_s_setprio(0); }

#define STAGE_A(T, MH) { int ts_ = (T) < 64 ? (T) : 63;                               \
    char* d_ = (char*)lds8 + ((T)&1)*65536 + (MH)*16384 + wid*1024;                   \
    g2l16(pA0[MH] + ts_*64, d_); g2l16(pA1[MH] + ts_*64, d_ + 8192); }

#define STAGE_B(T, NH) { int ts_ = (T) < 64 ? (T) : 63;                               \
    char* d_ = (char*)lds8 + ((T)&1)*65536 + 32768 + (NH)*16384 + wid*1024;           \
    g2l16(pB0[NH] + ts_*64, d_); g2l16(pB1[NH] + ts_*64, d_ + 8192); }

#define G8_MAINLOOP()                                                                 \
  STAGE_A(0,0); STAGE_B(0,1); STAGE_A(0,1); STAGE_B(0,0);                             \
  STAGE_A(1,0); STAGE_B(1,1); STAGE_A(1,1);                                           \
  VMC(6); BARSB();                                                                    \
  for (int i_ = 0; i_ < 32; ++i_) {                                                   \
    const int ta_ = 2 * i_;                                                           \
    READ_A(0,0); READ_B(0,0); STAGE_B(ta_+1, 0); BARSB(); MM16(0,0); BARSB();         \
    READ_B(1,0);              STAGE_A(ta_+2, 0); BARSB(); MM16(0,1); BARSB();         \
    READ_A(1,0);              STAGE_B(ta_+2, 1); BARSB(); MM16(1,1); BARSB();         \
    READ_B(0,0);              STAGE_A(ta_+2, 1); BARSB(); MM16(1,0); VMC(4); BARSB(); \
    READ_A(0,1); READ_B(0,1); STAGE_B(ta_+2, 0); BARSB(); MM16(0,0); BARSB();         \
    READ_B(1,1);              STAGE_A(ta_+3, 0); BARSB(); MM16(0,1); BARSB();         \
    READ_A(1,1);              STAGE_B(ta_+3, 1); BARSB(); MM16(1,1); BARSB();         \
    READ_B(0,1);              STAGE_A(ta_+3, 1); BARSB(); MM16(1,0); VMC(4); BARSB(); \
  }

// ---- O-projection GEMM: fp32 row-major out (8-phase core) ----
__global__ __launch_bounds__(512, 2) void k_gemm8(const u16* __restrict__ A, const u16* __restrict__ Bt,
                                                  float* __restrict__ Cp) {
  __shared__ u16 lds8[65536];  // 128 KB
  const int tid = threadIdx.x, wid = tid >> 6, l = tid & 63, g = l >> 4, li = l & 15;
  const int wr = wid >> 2, wc = wid & 3;
  const int bid = blockIdx.x;
  const int swz = (bid & 7) * 32 + (bid >> 3);
  const int m0 = (swz >> 4) * 256, n0 = (swz & 15) * 256;

  const int swc0 = (g * 16) ^ ((li & 7) << 4);
  const int swc1 = (64 + g * 16) ^ ((li & 7) << 4);
  const int arow = wr * 64 + li;
  const int brow = wc * 32 + li;

  const int l8a = tid * 16, l8b = 8192 + tid * 16;
  const int oa = l8a ^ (((l8a >> 7) & 7) << 4), ob = l8b ^ (((l8b >> 7) & 7) << 4);
  const int rl0 = oa >> 7, cb0 = oa & 127, rl1 = ob >> 7, cb1 = ob & 127;
  const int RA0 = (rl0 >> 6) * 128 + (rl0 & 63), RA1 = (rl1 >> 6) * 128 + (rl1 & 63);
  const int CB0 = (rl0 >> 5) * 64 + (rl0 & 31), CB1 = (rl1 >> 5) * 64 + (rl1 & 31);
  const u16 *pA0[2], *pA1[2], *pB0[2], *pB1[2];
#pragma unroll
  for (int mh = 0; mh < 2; ++mh) {
    pA0[mh] = A + (size_t)(m0 + RA0 + mh * 64) * 4096 + cb0 / 2;
    pA1[mh] = A + (size_t)(m0 + RA1 + mh * 64) * 4096 + cb1 / 2;
    pB0[mh] = Bt + (size_t)(n0 + CB0 + mh * 32) * 4096 + cb0 / 2;
    pB1[mh] = Bt + (size_t)(n0 + CB1 + mh * 32) * 4096 + cb1 / 2;
  }

  bf16x8 afr[4][2], bfr[2][2];
  const f32x4 vzero = {0.f, 0.f, 0.f, 0.f};
  f32x4 acc[2][4][2][2];
#pragma unroll
  for (int a = 0; a < 2; ++a)
#pragma unroll
    for (int b = 0; b < 4; ++b)
#pragma unroll
      for (int c = 0; c < 2; ++c)
#pragma unroll
        for (int d = 0; d < 2; ++d) acc[a][b][c][d] = vzero;

  G8_MAINLOOP();

#pragma unroll
  for (int mh = 0; mh < 2; ++mh)
#pragma unroll
    for (int mf = 0; mf < 4; ++mf)
#pragma unroll
      for (int nh = 0; nh < 2; ++nh)
#pragma unroll
        for (int nf = 0; nf < 2; ++nf)
#pragma unroll
          for (int j = 0; j < 4; ++j) {
            int row = m0 + wr * 128 + mh * 64 + mf * 16 + g * 4 + j;
            int col = n0 + wc * 64 + nh * 32 + nf * 16 + li;
            Cp[(size_t)row * 4096 + col] = acc[mh][mf][nh][nf][j];
          }
}

// ================= r9 16-wave GEMM core (1024 thr, 4-slot, vmcnt4) for QKV ==================
#define TB16(T, VMLIT, DOSTAGE)                                              \
  {                                                                          \
    asm volatile("s_waitcnt vmcnt(" VMLIT ")" ::: "memory");                 \
    __builtin_amdgcn_s_barrier();                                            \
    __builtin_amdgcn_sched_barrier(0);                                       \
    const u16* base_ = lds + ((T) & 3) * 16384;                              \
    bf16x8 bfr[4], afr[4];                                                   \
    _Pragma("unroll")                                                        \
    for (int nf = 0; nf < 4; ++nf)                                           \
      bfr[nf] = *(const bf16x8*)(base_ + boff + nf * 512);                   \
    _Pragma("unroll")                                                        \
    for (int mf = 0; mf < 4; ++mf)                                           \
      afr[mf] = *(const bf16x8*)(base_ + aoff + mf * 512);                   \
    if (DOSTAGE) stage((T) + 3);                                             \
    __builtin_amdgcn_s_setprio(1);                                           \
    _Pragma("unroll")                                                        \
    for (int mf = 0; mf < 4; ++mf)                                           \
      _Pragma("unroll")                                                      \
      for (int nf = 0; nf < 4; ++nf)                                         \
        acc[mf][nf] = mfma16(afr[mf], bfr[nf], acc[mf][nf]);                 \
    __builtin_amdgcn_s_setprio(0);                                           \
  }

#define LOOP16()                                                             \
  stage(0); stage(1); stage(2);                                              \
  for (int t = 0; t < 125; ++t) TB16(t, "4", true);                          \
  TB16(125, "4", false);                                                     \
  TB16(126, "2", false);                                                     \
  TB16(127, "0", false);

// ---- merged Q + segmented-KV GEMM, 400 blocks, 1024 thr (r9 core) ----
__global__ __launch_bounds__(1024, 4) void k_gemmQKV(const u16* __restrict__ Xb, const u16* __restrict__ WqT,
                                                     const u16* __restrict__ B0, const u16* __restrict__ B1,
                                                     const int* __restrict__ perm, const int* __restrict__ meta,
                                                     u16* __restrict__ Qr, u16* __restrict__ Ksel,
                                                     u16* __restrict__ Vsel) {
  __shared__ u16 lds[4 * 16384];
  const int tid = threadIdx.x, wid = tid >> 6, l = tid & 63, g = l >> 4, li = l & 15;
  const int wr = wid >> 2, wc = wid & 3;
  const int bid = blockIdx.x;
  const bool isQ = bid < 256;

  const int srow = wid * 16 + (l >> 2);
  const int sgg = (l & 3) ^ ((l >> 3) & 3);

  int m0 = 0, n0 = 0, bb = 0, tm = 0;
  const u16 *pA, *pB;
  if (isQ) {
    const int swz = (bid & 7) * 32 + (bid >> 3);
    m0 = (swz >> 4) * 256; n0 = (swz & 15) * 256;
    pA = Xb + (size_t)(m0 + srow) * 4096 + sgg * 8;
    pB = WqT + (size_t)(n0 + srow) * 4096 + sgg * 8;
  } else {
    const int kb = bid - 256;
    const int seg = kb >> 3;
    n0 = (kb & 7) * 256;
    bb = seg / 9; tm = seg % 9;
    const int nt0 = meta[bb * 2 + 1];
    const u16* Bt = (tm >= nt0) ? B1 : B0;
    int t0 = perm[bb * 2304 + tm * 256 + srow];
    if (t0 < 0) t0 = 0;
    pA = Xb + ((size_t)bb * 2048 + t0) * 4096 + sgg * 8;
    pB = Bt + (size_t)(n0 + srow) * 4096 + sgg * 8;
  }

  auto stage = [&](int t) {
    u16* da = (u16*)lds + (t & 3) * 16384 + wid * 512;
    g2l16(pA + t * 32, da);
    g2l16(pB + t * 32, da + 8192);
  };

  const int lsl8 = (g ^ ((li >> 1) & 3)) * 8;
  const int aoff = (wr * 64 + li) * 32 + lsl8;
  const int boff = 8192 + (wc * 64 + li) * 32 + lsl8;

  const f32x4 vzero = {0.f, 0.f, 0.f, 0.f};
  f32x4 acc[4][4];
#pragma unroll
  for (int m = 0; m < 4; ++m)
#pragma unroll
    for (int n = 0; n < 4; ++n) acc[m][n] = vzero;

  LOOP16();

  if (isQ) {
#pragma unroll
    for (int mf = 0; mf < 4; ++mf)
#pragma unroll
      for (int nf = 0; nf < 4; ++nf)
#pragma unroll
        for (int j = 0; j < 4; ++j) {
          int row = m0 + wr * 64 + mf * 16 + g * 4 + j;
          int col = n0 + wc * 64 + nf * 16 + li;
          int b = row >> 11, s = row & 2047, h = col >> 7, d = col & 127;
          Qr[(((size_t)(b * 32 + h)) * 2048 + s) * 128 + d] = f2bf(acc[mf][nf][j]);
        }
  } else {
#pragma unroll
    for (int mf = 0; mf < 4; ++mf)
#pragma unroll
      for (int nf = 0; nf < 4; ++nf)
#pragma unroll
        for (int j = 0; j < 4; ++j) {
          int slot = tm * 256 + wr * 64 + mf * 16 + g * 4 + j;
          int tok = perm[bb * 2304 + slot];
          if (tok >= 0) {
            int col = n0 + wc * 64 + nf * 16 + li;   // 0..2047
            int kv = col >> 10, hh = (col >> 7) & 7, d = col & 127;
            u16* dst = (kv ? Vsel : Ksel) + (((size_t)(bb * 8 + hh)) * 2048 + tok) * 128 + d;
            *dst = f2bf(acc[mf][nf][j]);
          }
        }
  }
}

// ---------------- K/V prep: table-RoPE(K) + V transpose to (d,s) ----------------
__global__ __launch_bounds__(256) void k_kvprep(const u16* __restrict__ Ks, const u16* __restrict__ Vs,
                                                const float2* __restrict__ tab,
                                                u16* __restrict__ Kr, u16* __restrict__ Vt) {
  __shared__ u16 Vl[64][136];
  int blk = blockIdx.x;
  int st = blk & 31, kvh = (blk >> 5) & 7, b = blk >> 8;
  int s0 = st * 64;
  int tid = threadIdx.x, wid = tid >> 6, l = tid & 63;
  size_t slab = (size_t)(b * 8 + kvh) * 2048;
  for (int rr = 0; rr < 16; ++rr) {
    int r = wid * 16 + rr;
    int s = s0 + r;
    const u16* ks = Ks + (slab + s) * 128;
    const u16* vs = Vs + (slab + s) * 128;
    float2 cs2 = tab[(size_t)s * 64 + l];
    float x1 = bf2f(ks[l]), x2 = bf2f(ks[l + 64]);
    u16* kd = Kr + (slab + s) * 128;
    kd[l] = f2bf(x1 * cs2.x - x2 * cs2.y);
    kd[l + 64] = f2bf(x2 * cs2.x + x1 * cs2.y);
    Vl[r][l] = vs[l];
    Vl[r][l + 64] = vs[l + 64];
  }
  __syncthreads();
  int d = tid >> 1, si0 = (tid & 1) * 32;
  u16* vd = Vt + ((size_t)(b * 8 + kvh) * 128 + d) * 2048 + s0 + si0;
#pragma unroll
  for (int k4 = 0; k4 < 8; ++k4) {
    ushort4 o;
    o.x = Vl[si0 + k4 * 4 + 0][d];
    o.y = Vl[si0 + k4 * 4 + 1][d];
    o.z = Vl[si0 + k4 * 4 + 2][d];
    o.w = Vl[si0 + k4 * 4 + 3][d];
    *(ushort4*)(vd + k4 * 4) = o;
  }
}

// ---------------- causal GQA flash attention: counted-vmcnt + XCD-affinity + table-fused Q-RoPE ----------------
__global__ __launch_bounds__(256, 2) void k_attn(const u16* __restrict__ Q, const u16* __restrict__ Kr,
                                                 const u16* __restrict__ Vt, const float2* __restrict__ tab,
                                                 u16* __restrict__ ctx) {
  __shared__ u16 Kl[2 * 64 * 128];
  __shared__ u16 Vl[2 * 128 * 64];
  const int id = blockIdx.x;
  const int gkv = id & 15, j = id >> 4;
  const int b = gkv >> 3, kvh = gkv & 7;
  const int h = kvh * 4 + (j & 3);
  const int p = j >> 2;
  const int bh = b * 32 + h;
  const int tid = threadIdx.x, w = tid >> 6, l = tid & 63;
  const int lo5 = l & 31, hi = l >> 5;
  const bool hib = hi != 0;
  const size_t kvslab = (size_t)(b * 8 + kvh) * 2048;
  const u16* Kg = Kr + kvslab * 128;
  const u16* Vg = Vt + kvslab * 128;  // (d, s) layout
  const float L2E = 1.4426950408889634f;

  auto stage = [&](int kt, int bi) {
#pragma unroll
    for (int i = 0; i < 4; ++i) {
      int c = w * 4 + i;
      int slot = c * 1024 + l * 16;
      {  // K tile: 64 rows x 256B, 16-slot xor swizzle
        int row = slot >> 8;
        int inner = (slot & 255) ^ ((row & 15) << 4);
        g2l16((const char*)Kg + kt * 16384 + row * 256 + inner,
              (char*)Kl + bi * 16384 + c * 1024);
      }
      {  // V tile: 128 rows (d) x 128B, 8-slot swizzle
        int row = slot >> 7;
        int inner = (slot & 127) ^ ((row & 7) << 4);
        g2l16((const char*)Vg + (size_t)row * 4096 + kt * 128 + inner,
              (char*)Vl + bi * 16384 + c * 1024);
      }
    }
  };

  for (int hf = 0; hf < 2; ++hf) {
    const int qi = hf ? (15 - p) : p;
    const int q0 = qi * 128;
    const int qlane = q0 + w * 32 + lo5;
    const u16* qrow = Q + ((size_t)bh * 2048 + qlane) * 128;
    bf16x8 qf[8];
#pragma unroll
    for (int kk = 0; kk < 8; ++kk) qf[kk] = *(const bf16x8*)(qrow + kk * 16 + hi * 8);
    // ---- fused RoPE(Q) + 1/sqrt(128) via precomputed table (pair (d,d+64) = (qf[kk],qf[kk+4])) ----
    {
      const float2* trow = tab + (size_t)qlane * 64;
      const float sc = 0.08838834764831845f;
#pragma unroll
      for (int kk = 0; kk < 4; ++kk)
#pragma unroll
        for (int e = 0; e < 8; ++e) {
          float2 cs2 = trow[kk * 16 + hi * 8 + e];
          float x1 = (float)qf[kk][e], x2 = (float)qf[kk + 4][e];
          qf[kk][e]     = (__bf16)((x1 * cs2.x - x2 * cs2.y) * sc);
          qf[kk + 4][e] = (__bf16)((x2 * cs2.x + x1 * cs2.y) * sc);
        }
    }

    f32x16 ot[4];
#pragma unroll
    for (int i = 0; i < 4; ++i) ot[i] = zero16();
    float m = -1e30f, ls = 0.f;

    const int nkt = 2 * qi + 2;  // >= 2
    stage(0, 0);
    stage(1, 1);
    for (int kt = 0; kt < nkt; ++kt) {
      if (kt + 1 < nkt) {
        asm volatile("s_waitcnt vmcnt(8)" ::: "memory");
      } else {
        asm volatile("s_waitcnt vmcnt(0)" ::: "memory");
      }
      __builtin_amdgcn_s_barrier();
      __builtin_amdgcn_sched_barrier(0);
      const char* kbase = (const char*)Kl + (kt & 1) * 16384;
      const char* vbase = (const char*)Vl + (kt & 1) * 16384;
      const int ktb = kt * 64;
      if (ktb <= q0 + w * 32 + 31) {  // wave-uniform active check
        // ---- QK^T swapped: st[mf] = S^T[k=mf*32+..][q] ----
        f32x16 st[2];
        st[0] = zero16(); st[1] = zero16();
#pragma unroll
        for (int kk = 0; kk < 8; ++kk) {
          bf16x8 kfr[2];
#pragma unroll
          for (int mf = 0; mf < 2; ++mf) {
            int row = mf * 32 + lo5;
            kfr[mf] = *(const bf16x8*)(kbase + row * 256 + ((kk * 32 + hi * 16) ^ ((row & 15) << 4)));
          }
          __builtin_amdgcn_s_setprio(1);
          st[0] = mfma32(kfr[0], qf[kk], st[0]);
          st[1] = mfma32(kfr[1], qf[kk], st[1]);
          __builtin_amdgcn_s_setprio(0);
        }
        // ---- causal mask (boundary tiles only) ----
        if (ktb + 63 > q0 + w * 32) {
#pragma unroll
          for (int mf = 0; mf < 2; ++mf)
#pragma unroll
            for (int r = 0; r < 16; ++r) {
              int kg = ktb + mf * 32 + (r & 3) + 8 * (r >> 2) + 4 * hi;
              if (kg > qlane) st[mf][r] = -3.0e38f;
            }
        }
        // ---- online softmax, fully in-register ----
        float t[16];
#pragma unroll
        for (int r = 0; r < 16; ++r) t[r] = fmaxf(st[0][r], st[1][r]);
#pragma unroll
        for (int s = 8; s >= 1; s >>= 1)
#pragma unroll
          for (int r = 0; r < s; ++r) t[r] = fmaxf(t[r], t[r + s]);
        float pmax = fmaxf(t[0], __shfl_xor(t[0], 32));
        if (!__all(pmax <= m + 8.f)) {  // T13 defer-max
          float nm = fmaxf(m, pmax);
          float resc = exp2f((m - nm) * L2E);
          m = nm;
          ls *= resc;
#pragma unroll
          for (int i = 0; i < 4; ++i)
#pragma unroll
            for (int r = 0; r < 16; ++r) ot[i][r] *= resc;
        }
#pragma unroll
        for (int mf = 0; mf < 2; ++mf)
#pragma unroll
          for (int r = 0; r < 16; ++r) st[mf][r] = exp2f((st[mf][r] - m) * L2E);
        float u[16];
#pragma unroll
        for (int r = 0; r < 16; ++r) u[r] = st[0][r] + st[1][r];
#pragma unroll
        for (int s = 8; s >= 1; s >>= 1)
#pragma unroll
          for (int r = 0; r < s; ++r) u[r] += u[r + s];
        ls += u[0] + __shfl_xor(u[0], 32);
        // ---- pack P^T -> bf16 B-frags (T12) ----
        u32 pkv[16];
#pragma unroll
        for (int mf = 0; mf < 2; ++mf)
#pragma unroll
          for (int tt = 0; tt < 8; ++tt) {
            u32 r;
            asm("v_cvt_pk_bf16_f32 %0, %1, %2" : "=v"(r) : "v"(st[mf][2 * tt]), "v"(st[mf][2 * tt + 1]));
            pkv[mf * 8 + tt] = r;
          }
        bf16x8 pfrag[4];
#pragma unroll
        for (int kk = 0; kk < 4; ++kk) {
          int c = (kk >> 1) * 8 + (kk & 1) * 4;
          u32 m0 = hib ? pkv[c + 2] : pkv[c + 0];
          u32 m1 = hib ? pkv[c + 3] : pkv[c + 1];
          u32 s0 = hib ? pkv[c + 0] : pkv[c + 2];
          u32 s1 = hib ? pkv[c + 1] : pkv[c + 3];
          u32 r0 = (u32)__shfl_xor((int)s0, 32);
          u32 r1 = (u32)__shfl_xor((int)s1, 32);
          u32x4 wv = {hib ? r0 : m0, hib ? r1 : m1, hib ? m0 : r0, hib ? m1 : r1};
          pfrag[kk] = __builtin_bit_cast(bf16x8, wv);
        }
        // ---- PV swapped ----
#pragma unroll
        for (int mfV = 0; mfV < 4; ++mfV) {
          int row = mfV * 32 + lo5;
          const char* vb = vbase + row * 128;
          int sw = (row & 7) << 4;
          bf16x8 vf[4];
#pragma unroll
          for (int kk = 0; kk < 4; ++kk)
            vf[kk] = *(const bf16x8*)(vb + ((kk * 32 + hi * 16) ^ sw));
          __builtin_amdgcn_s_setprio(1);
#pragma unroll
          for (int kk = 0; kk < 4; ++kk) ot[mfV] = mfma32(vf[kk], pfrag[kk], ot[mfV]);
          __builtin_amdgcn_s_setprio(0);
        }
      }
      __builtin_amdgcn_s_barrier();
      if (kt + 2 < nkt) stage(kt + 2, kt & 1);
    }
    // ---- epilogue ----
    float inv = 1.0f / ls;
    u16* crow = ctx + ((size_t)(b * 2048) + qlane) * 4096 + h * 128;
#pragma unroll
    for (int mfV = 0; mfV < 4; ++mfV)
#pragma unroll
      for (int rq = 0; rq < 4; ++rq) {
        ushort4 o4;
        o4.x = f2bf(ot[mfV][rq * 4 + 0] * inv);
        o4.y = f2bf(ot[mfV][rq * 4 + 1] * inv);
        o4.z = f2bf(ot[mfV][rq * 4 + 2] * inv);
        o4.w = f2bf(ot[mfV][rq * 4 + 3] * inv);
        *(ushort4*)(crow + mfV * 32 + rq * 8 + hi * 4) = o4;
      }
  }
}

extern "C" void kernel_launch(void* const* d_in, const int* in_sizes, int n_in,
                              void* d_out, int out_size, void* d_ws, size_t ws_size,
                              hipStream_t stream) {
  (void)in_sizes; (void)n_in; (void)out_size; (void)ws_size;
  const float* X   = (const float*)d_in[0];
  const int*   mod = (const int*)d_in[1];
  const int*   pos = (const int*)d_in[2];
  const float* Wq  = (const float*)d_in[3];
  const float* Wk0 = (const float*)d_in[4];
  const float* Wk1 = (const float*)d_in[5];
  const float* Wv0 = (const float*)d_in[6];
  const float* Wv1 = (const float*)d_in[7];
  const float* Wo  = (const float*)d_in[8];
  float* out = (float*)d_out;

  u16* p = (u16*)d_ws;
  auto take = [&](size_t n) { u16* r = p; p += n; return r; };
  u16* Xb    = take(16777216);  // X bf16 -> later ctx
  u16* WqT   = take(16777216);  // Wq^T -> later Kr | Vtr
  u16* WoT   = take(16777216);  // Wo^T
  u16* Wkv0T = take(8388608);   // [Wk0|Wv0]^T
  u16* Wkv1T = take(8388608);   // [Wk1|Wv1]^T
  u16* Qr    = take(16777216);  // (b,h,s,d)
  u16* Ksel  = take(4194304);
  u16* Vsel  = take(4194304);
  float2* tab = (float2*)take(524288);  // 2048 x 64 cos/sin (1 MB)
  int* perm  = (int*)take(9216);
  int* meta  = (int*)take(64);
  u16* Kr  = WqT;
  u16* Vtr = WqT + 4194304;
  u16* ctx = Xb;

  k_prep<<<dim3(29186), 256, 0, stream>>>(X, Wq, Wk0, Wv0, Wk1, Wv1, Wo, mod, pos,
                                          Xb, WqT, Wkv0T, Wkv1T, WoT, tab, perm, meta);

  k_gemmQKV<<<dim3(400), 1024, 0, stream>>>(Xb, WqT, Wkv0T, Wkv1T, perm, meta, Qr, Ksel, Vsel);

  k_kvprep<<<dim3(512), 256, 0, stream>>>(Ksel, Vsel, tab, Kr, Vtr);

  k_attn<<<dim3(512), 256, 0, stream>>>(Qr, Kr, Vtr, tab, ctx);

  k_gemm8<<<dim3(256), 512, 0, stream>>>(ctx, WoT, out);
}